// Round 8
// baseline (215.238 us; speedup 1.0000x reference)
//
#include <hip/hip_runtime.h>
#include <hip/hip_bf16.h>
#include <cstddef>

// Shapes (fixed):
// x_seq: (T=16, B=32, 1, 100, 368) binary {0,1} fp32
// conv1: w1 (16,1,5,5) s2 p2   -> (32,16,50,184)  [MFMA bf16 3-term split, LIF in acc]
// conv2: w2 (32,16,3,3) s2 p1  -> (32,32,25,92)   [MFMA bf16 3-term split, LIF in acc]
// convd: wd (64,32,3,3) s1 p1  -> (32,64,25,92), relu        [MFMA bf16, co-split]
// convT1: wt1 (64,32,4,4) s2 p1 -> (32,32,50,184), relu      [MFMA bf16, parity-split]
// convT2: wt2 (32,2,4,4) s2 p1  -> (32,2,100,368), softplus  [VALU, bf16 reads]

#define T_STEPS 16
#define NB 32
#define H0 100
#define W0 368
#define C1 16
#define H1 50
#define W1 184
#define C2 32
#define H2 25
#define W2 92
#define CD 64
#define WPR 6
#define SITES2 2300   // 25*92
#define SITES1 9200   // 50*184
#define NPOS1 (NB * H1 * W1)   // 294400

using f32x16 = __attribute__((ext_vector_type(16))) float;
using f32x4  = __attribute__((ext_vector_type(4))) float;
using s16x8  = __attribute__((ext_vector_type(8))) short;

__device__ inline unsigned short f2bf(float f) {
    union { float f; unsigned int u; } v; v.f = f;
    unsigned int r = v.u + 0x7fffu + ((v.u >> 16) & 1u);  // RNE
    return (unsigned short)(r >> 16);
}
__device__ inline float bf2f(unsigned short u) {
    union { unsigned int u; float f; } v; v.u = ((unsigned int)u) << 16;
    return v.f;
}
__device__ inline unsigned int pk2(float a, float b) {
    return (unsigned int)f2bf(a) | ((unsigned int)f2bf(b) << 16);
}
__device__ inline s16x8 ld8(const void* p) { return *reinterpret_cast<const s16x8*>(p); }

// ---------------- Kernel P: bit-pack binary input ----------------
// One wave per 64-bit output word; wave-uniform addressing, 32-bit only.
__global__ __launch_bounds__(256) void k_pack(const float* __restrict__ x,
                                              unsigned long long* __restrict__ xb) {
    int widx = blockIdx.x * 4 + (threadIdx.x >> 6);   // word index (wave-uniform)
    int lane = threadIdx.x & 63;
    int rowid = widx / WPR;                           // uniform const-div
    int wcol  = widx - rowid * WPR;
    int col = (wcol << 6) + lane;
    const float* rp = x + (size_t)rowid * W0;
    float v = 0.f;
    if (col < W0) v = rp[col];
    unsigned long long m = __ballot(v != 0.f);
    if (lane == 0) xb[widx] = m;
}

// ---------------- Kernel M: build 25-bit tap masks for all (t, site) ----------------
__global__ __launch_bounds__(256) void k_mask(const unsigned long long* __restrict__ xb,
                                              unsigned int* __restrict__ bm) {
    int gid = blockIdx.x * blockDim.x + threadIdx.x;
    int t = gid / NPOS1;
    int site = gid - t * NPOS1;
    int x1 = site % W1;
    int tq = site / W1;
    int y1 = tq % H1;
    int b  = tq / H1;
    const int iy0 = 2 * y1 - 2;
    const int ix0 = 2 * x1 - 2;
    const int wi = ix0 >> 6;
    const int sh = ix0 & 63;
    const unsigned long long* xp = xb + ((size_t)(t * NB + b) * H0) * WPR;
    unsigned int bits25 = 0;
#pragma unroll
    for (int ky = 0; ky < 5; ++ky) {
        int iy = iy0 + ky;
        if (iy < 0 || iy >= H0) continue;
        const unsigned long long* row = xp + (size_t)iy * WPR;
        unsigned long long a = (wi >= 0) ? row[wi] : 0ull;
        unsigned long long bw = (wi + 1 < WPR) ? row[wi + 1] : 0ull;
        unsigned long long chunk = a >> sh;
        if (sh) chunk |= (bw << (64 - sh));
        bits25 |= ((unsigned int)chunk & 31u) << (5 * ky);
    }
    bm[gid] = bits25;
}

// ---------------- Kernel A: conv1+LIF fused MFMA over 16 timesteps ----------------
__global__ __launch_bounds__(256) void k_snn1(const unsigned int* __restrict__ bm,
                                              const unsigned short* __restrict__ w1b3,
                                              unsigned char* __restrict__ s1b) {
    __shared__ uint4 lut[256];
    {
        int m = (int)threadIdx.x;  // exactly 256 threads
        unsigned int wv[4];
#pragma unroll
        for (int h = 0; h < 4; ++h) {
            unsigned int lo = (m >> (2 * h)) & 1u, hb = (m >> (2 * h + 1)) & 1u;
            wv[h] = (lo ? 0x3F80u : 0u) | (hb ? 0x3F800000u : 0u);
        }
        lut[m] = make_uint4(wv[0], wv[1], wv[2], wv[3]);
    }
    __syncthreads();

    int wave = threadIdx.x >> 6;
    int lane = threadIdx.x & 63;
    int col = lane & 15;   // site within group / A row (co)
    int hi  = lane >> 4;   // k-slice index
    int base = (blockIdx.x * 4 + wave) * 64;

    s16x8 af0 = ld8((const char*)w1b3 + (size_t)((0 * 16 + col) * 32 + hi * 8) * 2);
    s16x8 af1 = ld8((const char*)w1b3 + (size_t)((1 * 16 + col) * 32 + hi * 8) * 2);
    s16x8 af2 = ld8((const char*)w1b3 + (size_t)((2 * 16 + col) * 32 + hi * 8) * 2);

    f32x4 acc0 = {}, acc1 = {}, acc2 = {}, acc3 = {};

    unsigned int cm0, cm1, cm2, cm3;
    {
        const unsigned int* bp = bm + base;
        cm0 = bp[col]; cm1 = bp[16 + col]; cm2 = bp[32 + col]; cm3 = bp[48 + col];
    }

    for (int t = 0; t < T_STEPS; ++t) {
        unsigned int nm0 = 0, nm1 = 0, nm2 = 0, nm3 = 0;
        if (t < T_STEPS - 1) {
            const unsigned int* bp = bm + (size_t)(t + 1) * NPOS1 + base;
            nm0 = bp[col]; nm1 = bp[16 + col]; nm2 = bp[32 + col]; nm3 = bp[48 + col];
        }
#pragma unroll
        for (int e = 0; e < 4; ++e) {
            acc0[e] *= 0.5f; acc1[e] *= 0.5f; acc2[e] *= 0.5f; acc3[e] *= 0.5f;
        }
#pragma unroll
        for (int g = 0; g < 4; ++g) {
            unsigned int sb = (g == 0) ? cm0 : (g == 1) ? cm1 : (g == 2) ? cm2 : cm3;
            unsigned int byte = (sb >> (hi * 8)) & 0xFFu;
            s16x8 bf = *reinterpret_cast<const s16x8*>(&lut[byte]);
            f32x4& ac = (g == 0) ? acc0 : (g == 1) ? acc1 : (g == 2) ? acc2 : acc3;
            ac = __builtin_amdgcn_mfma_f32_16x16x32_bf16(af0, bf, ac, 0, 0, 0);
            ac = __builtin_amdgcn_mfma_f32_16x16x32_bf16(af1, bf, ac, 0, 0, 0);
            ac = __builtin_amdgcn_mfma_f32_16x16x32_bf16(af2, bf, ac, 0, 0, 0);
        }
#pragma unroll
        for (int g = 0; g < 4; ++g) {
            f32x4& ac = (g == 0) ? acc0 : (g == 1) ? acc1 : (g == 2) ? acc2 : acc3;
            unsigned int nib = 0;
#pragma unroll
            for (int e = 0; e < 4; ++e) {
                float v = ac[e];
                bool s = (v >= 1.0f);
                if (s) nib |= (1u << e);
                ac[e] = s ? 0.f : v;
            }
            unsigned int mk = nib << ((hi & 1) * 4);   // co = hi*4+e
            mk |= __shfl_xor(mk, 16, 64);
            if (hi == 0)
                s1b[(size_t)(t * 2 + 0) * NPOS1 + base + g * 16 + col] = (unsigned char)mk;
            else if (hi == 2)
                s1b[(size_t)(t * 2 + 1) * NPOS1 + base + g * 16 + col] = (unsigned char)mk;
        }
        cm0 = nm0; cm1 = nm1; cm2 = nm2; cm3 = nm3;
    }
}

// ---------------- Kernel B: conv2+LIF fused MFMA over 16 timesteps ----------------
__global__ __launch_bounds__(256) void k_snn2(const unsigned char* __restrict__ s1b,
                                              const unsigned short* __restrict__ w2b3,
                                              unsigned short* __restrict__ mem2bf) {
    __shared__ uint4 lut[256];
    {
        int m = (int)threadIdx.x;
        unsigned int wv[4];
#pragma unroll
        for (int h = 0; h < 4; ++h) {
            unsigned int lo = (m >> (2 * h)) & 1u, hb = (m >> (2 * h + 1)) & 1u;
            wv[h] = (lo ? 0x3F80u : 0u) | (hb ? 0x3F800000u : 0u);
        }
        lut[m] = make_uint4(wv[0], wv[1], wv[2], wv[3]);
    }
    __syncthreads();

    int wave = threadIdx.x >> 6;
    int lane = threadIdx.x & 63;
    int col = lane & 31, hi = lane >> 5;
    int gsite = (blockIdx.x * 4 + wave) * 32 + col;
    int b = gsite / SITES2;
    int rest = gsite % SITES2;
    int y2 = rest / W2, x2 = rest % W2;

    int toff[9]; bool tval[9];
#pragma unroll
    for (int ky = 0; ky < 3; ++ky)
#pragma unroll
        for (int kx = 0; kx < 3; ++kx) {
            int iy = 2 * y2 + ky - 1, ix = 2 * x2 + kx - 1;
            tval[ky * 3 + kx] = iy >= 0 && iy < H1 && ix >= 0 && ix < W1;
            toff[ky * 3 + kx] = iy * W1 + ix;
        }

    const char* ab = (const char*)w2b3;
    s16x8 a0[9], a1[9], a2[9];
#pragma unroll
    for (int s = 0; s < 9; ++s) {
        int ko = (s * 16 + hi * 8) * 2;
        a0[s] = ld8(ab + (col * 144) * 2 + ko);
        a1[s] = ld8(ab + ((32 + col) * 144) * 2 + ko);
        a2[s] = ld8(ab + ((64 + col) * 144) * 2 + ko);
    }

    f32x16 acc = {};

    for (int t = 0; t < T_STEPS; ++t) {
        const unsigned char* spk = s1b + (size_t)(t * 2 + hi) * NPOS1 + (size_t)b * (H1 * W1);
        unsigned int msk[9];
#pragma unroll
        for (int i = 0; i < 9; ++i)
            msk[i] = tval[i] ? (unsigned int)spk[toff[i]] : 0u;

#pragma unroll
        for (int e = 0; e < 16; ++e) acc[e] *= 0.5f;

#pragma unroll
        for (int s = 0; s < 9; ++s) {
            s16x8 bf = *reinterpret_cast<const s16x8*>(&lut[msk[s]]);
            acc = __builtin_amdgcn_mfma_f32_32x32x16_bf16(a0[s], bf, acc, 0, 0, 0);
            acc = __builtin_amdgcn_mfma_f32_32x32x16_bf16(a1[s], bf, acc, 0, 0, 0);
            acc = __builtin_amdgcn_mfma_f32_32x32x16_bf16(a2[s], bf, acc, 0, 0, 0);
        }
#pragma unroll
        for (int e = 0; e < 16; ++e) {
            float v = acc[e];
            acc[e] = (v >= 1.0f) ? 0.f : v;
        }
    }

    char* obase = (char*)(mem2bf + (size_t)gsite * C2);
#pragma unroll
    for (int q = 0; q < 4; ++q) {
        int co = 8 * q + 4 * hi;
        uint2 u;
        u.x = pk2(acc[4 * q + 0], acc[4 * q + 1]);
        u.y = pk2(acc[4 * q + 2], acc[4 * q + 3]);
        *(uint2*)(obase + co * 2) = u;
    }
}

// ---------------- Kernel R: repack weights ----------------
__global__ __launch_bounds__(256) void k_repackb(const float* __restrict__ wd,
                                                 const float* __restrict__ wt1,
                                                 const float* __restrict__ wt2,
                                                 const float* __restrict__ w2,
                                                 const float* __restrict__ w1,
                                                 unsigned short* __restrict__ wdb,
                                                 unsigned short* __restrict__ wt1b,
                                                 float* __restrict__ wt2k,
                                                 unsigned short* __restrict__ w2b3,
                                                 unsigned short* __restrict__ w1b3) {
    int gid = blockIdx.x * blockDim.x + threadIdx.x;
    if (gid < 64 * 288) {
        int co = gid / 288, k = gid % 288;
        int tap = k >> 5, ci = k & 31;
        wdb[gid] = f2bf(wd[((size_t)co * C2 + ci) * 9 + tap]);
    } else if (gid < 64 * 288 + 4 * 32 * 256) {
        int j = gid - 64 * 288;
        int par = j >> 13, co = (j >> 8) & 31, k = j & 255;
        int tap = k >> 6, ci = k & 63;
        int ty = tap >> 1, tx = tap & 1;
        int ry = par >> 1, rx = par & 1;
        int ky = ry ? (ty ? 0 : 2) : (ty ? 3 : 1);
        int kx = rx ? (tx ? 0 : 2) : (tx ? 3 : 1);
        wt1b[j] = f2bf(wt1[(((size_t)ci * 32 + co) * 4 + ky) * 4 + kx]);
    } else if (gid < 64 * 288 + 4 * 32 * 256 + 1024) {
        int j = gid - (64 * 288 + 4 * 32 * 256);
        int par = j >> 8, tap = (j >> 6) & 3, ci = (j >> 1) & 31, co = j & 1;
        int ty = tap >> 1, tx = tap & 1;
        int ry = par >> 1, rx = par & 1;
        int ky = ry ? (ty ? 0 : 2) : (ty ? 3 : 1);
        int kx = rx ? (tx ? 0 : 2) : (tx ? 3 : 1);
        wt2k[j] = wt2[(((size_t)ci * 2 + co) * 4 + ky) * 4 + kx];
    } else if (gid < 64 * 288 + 4 * 32 * 256 + 1024 + 3 * 32 * 144) {
        int j = gid - (64 * 288 + 4 * 32 * 256 + 1024);
        int p = j / 4608, rem = j % 4608;
        int co = rem / 144, k = rem % 144;
        int tap = k / 16, ci = k % 16;
        float w = w2[((size_t)co * C1 + ci) * 9 + tap];
        unsigned short b0 = f2bf(w);
        float r1 = w - bf2f(b0);
        unsigned short b1 = f2bf(r1);
        float r2 = r1 - bf2f(b1);
        unsigned short b2 = f2bf(r2);
        w2b3[j] = (p == 0) ? b0 : (p == 1) ? b1 : b2;
    } else if (gid < 64 * 288 + 4 * 32 * 256 + 1024 + 3 * 32 * 144 + 3 * 16 * 32) {
        int j = gid - (64 * 288 + 4 * 32 * 256 + 1024 + 3 * 32 * 144);
        int p = j / 512, rem = j % 512;
        int co = rem / 32, k = rem % 32;
        float w = (k < 25) ? w1[co * 25 + k] : 0.f;
        unsigned short b0 = f2bf(w);
        float r1 = w - bf2f(b0);
        unsigned short b1 = f2bf(r1);
        float r2 = r1 - bf2f(b1);
        unsigned short b2 = f2bf(r2);
        w1b3[j] = (p == 0) ? b0 : (p == 1) ? b1 : b2;
    }
}

// ---------------- Kernel C: convd via MFMA, co-split for TLP ----------------
// wave: 32co x 32 sites; grid(18, cog=2, 32)
__global__ __launch_bounds__(256) void k_convd(const unsigned short* __restrict__ mem2bf,
                                               const unsigned short* __restrict__ wdb,
                                               const float* __restrict__ bd,
                                               unsigned short* __restrict__ h1bf) {
    int wave = threadIdx.x >> 6;
    int lane = threadIdx.x & 63;
    int col = lane & 31, hi = lane >> 5;
    int cog = blockIdx.y;
    int b = blockIdx.z;
    int n0 = (blockIdx.x * 4 + wave) * 32;
    int site = n0 + col;
    bool sval = site < SITES2;
    int sc = sval ? site : 0;
    int yy = sc / W2, xx = sc % W2;

    const char* ibase = (const char*)(mem2bf + (size_t)b * SITES2 * C2);
    int toff[9];
    bool tval[9];
#pragma unroll
    for (int ky = 0; ky < 3; ++ky)
#pragma unroll
        for (int kx = 0; kx < 3; ++kx) {
            int iy = yy + ky - 1, ix = xx + kx - 1;
            bool v = sval && iy >= 0 && iy < H2 && ix >= 0 && ix < W2;
            tval[ky * 3 + kx] = v;
            toff[ky * 3 + kx] = (iy * W2 + ix) * (C2 * 2);
        }

    const char* abase = (const char*)wdb;
    f32x16 acc = {};
    const s16x8 zero = {0, 0, 0, 0, 0, 0, 0, 0};
#pragma unroll
    for (int s = 0; s < 18; ++s) {
        int tap = s >> 1;
        int boff = (s & 1) * 32 + hi * 16;
        s16x8 bf = tval[tap] ? ld8(ibase + toff[tap] + boff) : zero;
        s16x8 a = ld8(abase + (cog * 32 + col) * 576 + s * 32 + hi * 16);
        acc = __builtin_amdgcn_mfma_f32_32x32x16_bf16(a, bf, acc, 0, 0, 0);
    }
    if (!sval) return;
    char* obase = (char*)(h1bf + ((size_t)b * SITES2 + site) * CD);
#pragma unroll
    for (int q = 0; q < 4; ++q) {
        int co = cog * 32 + 8 * q + 4 * hi;
        float v0 = fmaxf(acc[4 * q + 0] + bd[co + 0], 0.f);
        float v1 = fmaxf(acc[4 * q + 1] + bd[co + 1], 0.f);
        float v2 = fmaxf(acc[4 * q + 2] + bd[co + 2], 0.f);
        float v3 = fmaxf(acc[4 * q + 3] + bd[co + 3], 0.f);
        uint2 u; u.x = pk2(v0, v1); u.y = pk2(v2, v3);
        *(uint2*)(obase + co * 2) = u;
    }
}

// ---------------- Kernel D: convt1 via MFMA, parity-split, 1 tile/wave ----------------
// wave: 32co x 32 sites; grid(18, par=4, 32)
__global__ __launch_bounds__(256) void k_convt1(const unsigned short* __restrict__ h1bf,
                                                const unsigned short* __restrict__ wt1b,
                                                const float* __restrict__ bt1,
                                                unsigned short* __restrict__ h2bf) {
    int wave = threadIdx.x >> 6;
    int lane = threadIdx.x & 63;
    int col = lane & 31, hi = lane >> 5;
    int par = blockIdx.y;
    int ry = par >> 1, rx = par & 1;
    int b = blockIdx.z;
    int n0 = (blockIdx.x * 4 + wave) * 32;

    const char* ibase = (const char*)(h1bf + (size_t)b * SITES2 * CD);
    int site = n0 + col;
    bool sv = site < SITES2;
    int sc = sv ? site : 0;
    int m = sc / W2, n = sc % W2;
    int iy1 = m + (ry ? 1 : -1);
    int ix1 = n + (rx ? 1 : -1);
    bool y1v = iy1 >= 0 && iy1 < H2;
    bool x1v = ix1 >= 0 && ix1 < W2;
    int toff[4]; bool tval[4];
#pragma unroll
    for (int t = 0; t < 4; ++t) {
        int ty = t >> 1, tx = t & 1;
        int iy = ty ? iy1 : m;
        int ix = tx ? ix1 : n;
        tval[t] = sv && (ty ? y1v : true) && (tx ? x1v : true);
        toff[t] = (iy * W2 + ix) * (CD * 2);
    }

    const char* abase = (const char*)(wt1b + (size_t)par * 32 * 256);
    f32x16 acc = {};
    const s16x8 zero = {0, 0, 0, 0, 0, 0, 0, 0};
#pragma unroll
    for (int s = 0; s < 16; ++s) {
        int tap = s >> 2;
        int boff = (s & 3) * 32 + hi * 16;
        s16x8 bf = tval[tap] ? ld8(ibase + toff[tap] + boff) : zero;
        s16x8 a = ld8(abase + col * 512 + s * 32 + hi * 16);
        acc = __builtin_amdgcn_mfma_f32_32x32x16_bf16(a, bf, acc, 0, 0, 0);
    }
    if (!sv) return;
    int oy = 2 * m + ry, ox = 2 * n + rx;
    char* obase = (char*)(h2bf + ((size_t)b * SITES1 + (size_t)oy * W1 + ox) * C2);
#pragma unroll
    for (int q = 0; q < 4; ++q) {
        int co = 8 * q + 4 * hi;
        float v0 = fmaxf(acc[4 * q + 0] + bt1[co + 0], 0.f);
        float v1 = fmaxf(acc[4 * q + 1] + bt1[co + 1], 0.f);
        float v2 = fmaxf(acc[4 * q + 2] + bt1[co + 2], 0.f);
        float v3 = fmaxf(acc[4 * q + 3] + bt1[co + 3], 0.f);
        uint2 u; u.x = pk2(v0, v1); u.y = pk2(v2, v3);
        *(uint2*)(obase + co * 2) = u;
    }
}

// ---------------- Kernel E: convt2 VALU, bf16 channel-last input ----------------
__global__ __launch_bounds__(256) void k_convt2(const unsigned short* __restrict__ h2bf,
                                                const float* __restrict__ wt2k,
                                                const float* __restrict__ bt2,
                                                float* __restrict__ out) {
    int i = blockIdx.x * blockDim.x + threadIdx.x;
    if (i >= SITES1) return;
    int par = blockIdx.y;
    int ry = par >> 1, rx = par & 1;
    int b = blockIdx.z;
    int m = i / W1, n = i % W1;
    int iy1 = m + (ry ? 1 : -1);
    int ix1 = n + (rx ? 1 : -1);
    bool y1v = iy1 >= 0 && iy1 < H1;
    bool x1v = ix1 >= 0 && ix1 < W1;

    float a0 = bt2[0], a1 = bt2[1];
    const unsigned short* ib = h2bf + (size_t)b * SITES1 * C2;
#pragma unroll
    for (int t = 0; t < 4; ++t) {
        int ty = t >> 1, tx = t & 1;
        if ((ty && !y1v) || (tx && !x1v)) continue;
        int iy = ty ? iy1 : m;
        int ix = tx ? ix1 : n;
        const unsigned short* p = ib + ((size_t)iy * W1 + ix) * C2;
        const float* w = wt2k + ((size_t)par * 4 + t) * 64;
#pragma unroll
        for (int g = 0; g < 4; ++g) {
            s16x8 v8 = ld8(p + g * 8);
#pragma unroll
            for (int e = 0; e < 8; ++e) {
                float v = bf2f((unsigned short)v8[e]);
                int ci = g * 8 + e;
                a0 += v * w[2 * ci];
                a1 += v * w[2 * ci + 1];
            }
        }
    }
    int oy = 2 * m + ry, ox = 2 * n + rx;
    size_t base_o = (size_t)b * (H0 * W0) + (size_t)oy * W0 + ox;
    out[base_o] = fmaxf(a0, 0.f) + log1pf(expf(-fabsf(a0)));
    out[(size_t)NB * H0 * W0 + base_o] = fmaxf(a1, 0.f) + log1pf(expf(-fabsf(a1)));
}

extern "C" void kernel_launch(void* const* d_in, const int* in_sizes, int n_in,
                              void* d_out, int out_size, void* d_ws, size_t ws_size,
                              hipStream_t stream) {
    const float* x   = (const float*)d_in[0];
    const float* w1  = (const float*)d_in[1];
    const float* w2  = (const float*)d_in[2];
    const float* wd  = (const float*)d_in[3];
    const float* bd  = (const float*)d_in[4];
    const float* wt1 = (const float*)d_in[5];
    const float* bt1 = (const float*)d_in[6];
    const float* wt2 = (const float*)d_in[7];
    const float* bt2 = (const float*)d_in[8];
    float* out = (float*)d_out;

    char* ws = (char*)d_ws;
    // workspace (bytes):
    unsigned char* s1b     = (unsigned char*)(ws);               //  9,420,800 (16t x 2 planes x 294400)
    unsigned short* mem2bf = (unsigned short*)(ws + 9420800);    //  4,710,400
    unsigned short* h1bf   = (unsigned short*)(ws + 14131200);   //  9,420,800
    unsigned short* h2bf   = (unsigned short*)(ws + 23552000);   // 18,841,600
    unsigned long long* xb = (unsigned long long*)(ws + 42393600); // 2,457,600
    unsigned short* wdb    = (unsigned short*)(ws + 44851200);   //     36,864
    unsigned short* wt1b   = (unsigned short*)(ws + 44888064);   //     65,536
    float* wt2k            = (float*)(ws + 44953600);            //      4,096
    unsigned short* w2b3   = (unsigned short*)(ws + 44957696);   //     27,648
    unsigned short* w1b3   = (unsigned short*)(ws + 44985344);   //      3,072
    unsigned int* bm       = (unsigned int*)(ws + 44988416);     // 18,841,600 -> ends 63,830,016

    {
        int n = 64 * 288 + 4 * 32 * 256 + 1024 + 3 * 32 * 144 + 3 * 16 * 32; // 67584
        k_repackb<<<(n + 255) / 256, 256, 0, stream>>>(wd, wt1, wt2, w2, w1,
                                                       wdb, wt1b, wt2k, w2b3, w1b3);
    }
    {
        // 307200 words / 4 waves per block = 76800 blocks exactly
        k_pack<<<76800, 256, 0, stream>>>(x, xb);
    }
    {
        // 16*294400/256 = 18400 blocks exactly
        k_mask<<<18400, 256, 0, stream>>>(xb, bm);
    }
    {
        // 294400 sites / 64 per wave / 4 waves per block = 1150 blocks exactly
        k_snn1<<<1150, 256, 0, stream>>>(bm, w1b3, s1b);
    }
    {
        // 73600 sites / 32 per wave / 4 waves per block = 575 blocks exactly
        k_snn2<<<575, 256, 0, stream>>>(s1b, w2b3, mem2bf);
    }
    {
        dim3 g(18, 2, NB);
        k_convd<<<g, 256, 0, stream>>>(mem2bf, wdb, bd, h1bf);
    }
    {
        dim3 g(18, 4, NB);
        k_convt1<<<g, 256, 0, stream>>>(h1bf, wt1b, bt1, h2bf);
    }
    {
        dim3 g(36, 4, NB);
        k_convt2<<<g, 256, 0, stream>>>(h2bf, wt2k, bt2, out);
    }
}

// Round 9
// 212.636 us; speedup vs baseline: 1.0122x; 1.0122x over previous
//
#include <hip/hip_runtime.h>
#include <hip/hip_bf16.h>
#include <cstddef>

// Shapes (fixed):
// x_seq: (T=16, B=32, 1, 100, 368) binary {0,1} fp32
// conv1: w1 (16,1,5,5) s2 p2   -> (32,16,50,184)  [MFMA bf16 3-term split, LIF in acc]
// conv2: w2 (32,16,3,3) s2 p1  -> (32,32,25,92)   [MFMA bf16 3-term split, LIF in acc]
// convd: wd (64,32,3,3) s1 p1  -> (32,64,25,92), relu        [MFMA bf16, co-split]
// convT1: wt1 (64,32,4,4) s2 p1 -> (32,32,50,184), relu      [MFMA bf16, parity-per-wave]
// convT2: wt2 (32,2,4,4) s2 p1  -> (32,2,100,368), softplus  [VALU, bf16 reads]

#define T_STEPS 16
#define NB 32
#define H0 100
#define W0 368
#define C1 16
#define H1 50
#define W1 184
#define C2 32
#define H2 25
#define W2 92
#define CD 64
#define WPR 6
#define SITES2 2300   // 25*92
#define SITES1 9200   // 50*184
#define NPOS1 (NB * H1 * W1)   // 294400

using f32x16 = __attribute__((ext_vector_type(16))) float;
using f32x4  = __attribute__((ext_vector_type(4))) float;
using s16x8  = __attribute__((ext_vector_type(8))) short;

__device__ inline unsigned short f2bf(float f) {
    union { float f; unsigned int u; } v; v.f = f;
    unsigned int r = v.u + 0x7fffu + ((v.u >> 16) & 1u);  // RNE
    return (unsigned short)(r >> 16);
}
__device__ inline float bf2f(unsigned short u) {
    union { unsigned int u; float f; } v; v.u = ((unsigned int)u) << 16;
    return v.f;
}
__device__ inline unsigned int pk2(float a, float b) {
    return (unsigned int)f2bf(a) | ((unsigned int)f2bf(b) << 16);
}
__device__ inline s16x8 ld8(const void* p) { return *reinterpret_cast<const s16x8*>(p); }

// ---------------- Kernel P: bit-pack binary input ----------------
// One wave per 64-bit output word; wave-uniform addressing, 32-bit only.
__global__ __launch_bounds__(256) void k_pack(const float* __restrict__ x,
                                              unsigned long long* __restrict__ xb) {
    int widx = blockIdx.x * 4 + (threadIdx.x >> 6);   // word index (wave-uniform)
    int lane = threadIdx.x & 63;
    int rowid = widx / WPR;                           // uniform const-div
    int wcol  = widx - rowid * WPR;
    int col = (wcol << 6) + lane;
    const float* rp = x + (size_t)rowid * W0;
    float v = 0.f;
    if (col < W0) v = rp[col];
    unsigned long long m = __ballot(v != 0.f);
    if (lane == 0) xb[widx] = m;
}

// ---------------- Kernel M: build 25-bit tap masks for all (t, site) ----------------
__global__ __launch_bounds__(256) void k_mask(const unsigned long long* __restrict__ xb,
                                              unsigned int* __restrict__ bm) {
    int gid = blockIdx.x * blockDim.x + threadIdx.x;
    int t = gid / NPOS1;
    int site = gid - t * NPOS1;
    int x1 = site % W1;
    int tq = site / W1;
    int y1 = tq % H1;
    int b  = tq / H1;
    const int iy0 = 2 * y1 - 2;
    const int ix0 = 2 * x1 - 2;
    const int wi = ix0 >> 6;
    const int sh = ix0 & 63;
    const unsigned long long* xp = xb + ((size_t)(t * NB + b) * H0) * WPR;
    unsigned int bits25 = 0;
#pragma unroll
    for (int ky = 0; ky < 5; ++ky) {
        int iy = iy0 + ky;
        if (iy < 0 || iy >= H0) continue;
        const unsigned long long* row = xp + (size_t)iy * WPR;
        unsigned long long a = (wi >= 0) ? row[wi] : 0ull;
        unsigned long long bw = (wi + 1 < WPR) ? row[wi + 1] : 0ull;
        unsigned long long chunk = a >> sh;
        if (sh) chunk |= (bw << (64 - sh));
        bits25 |= ((unsigned int)chunk & 31u) << (5 * ky);
    }
    bm[gid] = bits25;
}

// ---------------- Kernel A: conv1+LIF fused MFMA over 16 timesteps ----------------
__global__ __launch_bounds__(256) void k_snn1(const unsigned int* __restrict__ bm,
                                              const unsigned short* __restrict__ w1b3,
                                              unsigned char* __restrict__ s1b) {
    __shared__ uint4 lut[256];
    {
        int m = (int)threadIdx.x;  // exactly 256 threads
        unsigned int wv[4];
#pragma unroll
        for (int h = 0; h < 4; ++h) {
            unsigned int lo = (m >> (2 * h)) & 1u, hb = (m >> (2 * h + 1)) & 1u;
            wv[h] = (lo ? 0x3F80u : 0u) | (hb ? 0x3F800000u : 0u);
        }
        lut[m] = make_uint4(wv[0], wv[1], wv[2], wv[3]);
    }
    __syncthreads();

    int wave = threadIdx.x >> 6;
    int lane = threadIdx.x & 63;
    int col = lane & 15;   // site within group / A row (co)
    int hi  = lane >> 4;   // k-slice index
    int base = (blockIdx.x * 4 + wave) * 64;

    s16x8 af0 = ld8((const char*)w1b3 + (size_t)((0 * 16 + col) * 32 + hi * 8) * 2);
    s16x8 af1 = ld8((const char*)w1b3 + (size_t)((1 * 16 + col) * 32 + hi * 8) * 2);
    s16x8 af2 = ld8((const char*)w1b3 + (size_t)((2 * 16 + col) * 32 + hi * 8) * 2);

    f32x4 acc0 = {}, acc1 = {}, acc2 = {}, acc3 = {};

    unsigned int cm0, cm1, cm2, cm3;
    {
        const unsigned int* bp = bm + base;
        cm0 = bp[col]; cm1 = bp[16 + col]; cm2 = bp[32 + col]; cm3 = bp[48 + col];
    }

    for (int t = 0; t < T_STEPS; ++t) {
        unsigned int nm0 = 0, nm1 = 0, nm2 = 0, nm3 = 0;
        if (t < T_STEPS - 1) {
            const unsigned int* bp = bm + (size_t)(t + 1) * NPOS1 + base;
            nm0 = bp[col]; nm1 = bp[16 + col]; nm2 = bp[32 + col]; nm3 = bp[48 + col];
        }
#pragma unroll
        for (int e = 0; e < 4; ++e) {
            acc0[e] *= 0.5f; acc1[e] *= 0.5f; acc2[e] *= 0.5f; acc3[e] *= 0.5f;
        }
#pragma unroll
        for (int g = 0; g < 4; ++g) {
            unsigned int sb = (g == 0) ? cm0 : (g == 1) ? cm1 : (g == 2) ? cm2 : cm3;
            unsigned int byte = (sb >> (hi * 8)) & 0xFFu;
            s16x8 bf = *reinterpret_cast<const s16x8*>(&lut[byte]);
            f32x4& ac = (g == 0) ? acc0 : (g == 1) ? acc1 : (g == 2) ? acc2 : acc3;
            ac = __builtin_amdgcn_mfma_f32_16x16x32_bf16(af0, bf, ac, 0, 0, 0);
            ac = __builtin_amdgcn_mfma_f32_16x16x32_bf16(af1, bf, ac, 0, 0, 0);
            ac = __builtin_amdgcn_mfma_f32_16x16x32_bf16(af2, bf, ac, 0, 0, 0);
        }
#pragma unroll
        for (int g = 0; g < 4; ++g) {
            f32x4& ac = (g == 0) ? acc0 : (g == 1) ? acc1 : (g == 2) ? acc2 : acc3;
            unsigned int nib = 0;
#pragma unroll
            for (int e = 0; e < 4; ++e) {
                float v = ac[e];
                bool s = (v >= 1.0f);
                if (s) nib |= (1u << e);
                ac[e] = s ? 0.f : v;
            }
            unsigned int mk = nib << ((hi & 1) * 4);   // co = hi*4+e
            mk |= __shfl_xor(mk, 16, 64);
            if (hi == 0)
                s1b[(size_t)(t * 2 + 0) * NPOS1 + base + g * 16 + col] = (unsigned char)mk;
            else if (hi == 2)
                s1b[(size_t)(t * 2 + 1) * NPOS1 + base + g * 16 + col] = (unsigned char)mk;
        }
        cm0 = nm0; cm1 = nm1; cm2 = nm2; cm3 = nm3;
    }
}

// ---------------- Kernel B: conv2+LIF fused MFMA over 16 timesteps ----------------
__global__ __launch_bounds__(256) void k_snn2(const unsigned char* __restrict__ s1b,
                                              const unsigned short* __restrict__ w2b3,
                                              unsigned short* __restrict__ mem2bf) {
    __shared__ uint4 lut[256];
    {
        int m = (int)threadIdx.x;
        unsigned int wv[4];
#pragma unroll
        for (int h = 0; h < 4; ++h) {
            unsigned int lo = (m >> (2 * h)) & 1u, hb = (m >> (2 * h + 1)) & 1u;
            wv[h] = (lo ? 0x3F80u : 0u) | (hb ? 0x3F800000u : 0u);
        }
        lut[m] = make_uint4(wv[0], wv[1], wv[2], wv[3]);
    }
    __syncthreads();

    int wave = threadIdx.x >> 6;
    int lane = threadIdx.x & 63;
    int col = lane & 31, hi = lane >> 5;
    int gsite = (blockIdx.x * 4 + wave) * 32 + col;
    int b = gsite / SITES2;
    int rest = gsite % SITES2;
    int y2 = rest / W2, x2 = rest % W2;

    int toff[9]; bool tval[9];
#pragma unroll
    for (int ky = 0; ky < 3; ++ky)
#pragma unroll
        for (int kx = 0; kx < 3; ++kx) {
            int iy = 2 * y2 + ky - 1, ix = 2 * x2 + kx - 1;
            tval[ky * 3 + kx] = iy >= 0 && iy < H1 && ix >= 0 && ix < W1;
            toff[ky * 3 + kx] = iy * W1 + ix;
        }

    const char* ab = (const char*)w2b3;
    s16x8 a0[9], a1[9], a2[9];
#pragma unroll
    for (int s = 0; s < 9; ++s) {
        int ko = (s * 16 + hi * 8) * 2;
        a0[s] = ld8(ab + (col * 144) * 2 + ko);
        a1[s] = ld8(ab + ((32 + col) * 144) * 2 + ko);
        a2[s] = ld8(ab + ((64 + col) * 144) * 2 + ko);
    }

    f32x16 acc = {};

    for (int t = 0; t < T_STEPS; ++t) {
        const unsigned char* spk = s1b + (size_t)(t * 2 + hi) * NPOS1 + (size_t)b * (H1 * W1);
        unsigned int msk[9];
#pragma unroll
        for (int i = 0; i < 9; ++i)
            msk[i] = tval[i] ? (unsigned int)spk[toff[i]] : 0u;

#pragma unroll
        for (int e = 0; e < 16; ++e) acc[e] *= 0.5f;

#pragma unroll
        for (int s = 0; s < 9; ++s) {
            s16x8 bf = *reinterpret_cast<const s16x8*>(&lut[msk[s]]);
            acc = __builtin_amdgcn_mfma_f32_32x32x16_bf16(a0[s], bf, acc, 0, 0, 0);
            acc = __builtin_amdgcn_mfma_f32_32x32x16_bf16(a1[s], bf, acc, 0, 0, 0);
            acc = __builtin_amdgcn_mfma_f32_32x32x16_bf16(a2[s], bf, acc, 0, 0, 0);
        }
#pragma unroll
        for (int e = 0; e < 16; ++e) {
            float v = acc[e];
            acc[e] = (v >= 1.0f) ? 0.f : v;
        }
    }

    char* obase = (char*)(mem2bf + (size_t)gsite * C2);
#pragma unroll
    for (int q = 0; q < 4; ++q) {
        int co = 8 * q + 4 * hi;
        uint2 u;
        u.x = pk2(acc[4 * q + 0], acc[4 * q + 1]);
        u.y = pk2(acc[4 * q + 2], acc[4 * q + 3]);
        *(uint2*)(obase + co * 2) = u;
    }
}

// ---------------- Kernel R: repack weights ----------------
__global__ __launch_bounds__(256) void k_repackb(const float* __restrict__ wd,
                                                 const float* __restrict__ wt1,
                                                 const float* __restrict__ wt2,
                                                 const float* __restrict__ w2,
                                                 const float* __restrict__ w1,
                                                 unsigned short* __restrict__ wdb,
                                                 unsigned short* __restrict__ wt1b,
                                                 float* __restrict__ wt2k,
                                                 unsigned short* __restrict__ w2b3,
                                                 unsigned short* __restrict__ w1b3) {
    int gid = blockIdx.x * blockDim.x + threadIdx.x;
    if (gid < 64 * 288) {
        int co = gid / 288, k = gid % 288;
        int tap = k >> 5, ci = k & 31;
        wdb[gid] = f2bf(wd[((size_t)co * C2 + ci) * 9 + tap]);
    } else if (gid < 64 * 288 + 4 * 32 * 256) {
        int j = gid - 64 * 288;
        int par = j >> 13, co = (j >> 8) & 31, k = j & 255;
        int tap = k >> 6, ci = k & 63;
        int ty = tap >> 1, tx = tap & 1;
        int ry = par >> 1, rx = par & 1;
        int ky = ry ? (ty ? 0 : 2) : (ty ? 3 : 1);
        int kx = rx ? (tx ? 0 : 2) : (tx ? 3 : 1);
        wt1b[j] = f2bf(wt1[(((size_t)ci * 32 + co) * 4 + ky) * 4 + kx]);
    } else if (gid < 64 * 288 + 4 * 32 * 256 + 1024) {
        int j = gid - (64 * 288 + 4 * 32 * 256);
        int par = j >> 8, tap = (j >> 6) & 3, ci = (j >> 1) & 31, co = j & 1;
        int ty = tap >> 1, tx = tap & 1;
        int ry = par >> 1, rx = par & 1;
        int ky = ry ? (ty ? 0 : 2) : (ty ? 3 : 1);
        int kx = rx ? (tx ? 0 : 2) : (tx ? 3 : 1);
        wt2k[j] = wt2[(((size_t)ci * 2 + co) * 4 + ky) * 4 + kx];
    } else if (gid < 64 * 288 + 4 * 32 * 256 + 1024 + 3 * 32 * 144) {
        int j = gid - (64 * 288 + 4 * 32 * 256 + 1024);
        int p = j / 4608, rem = j % 4608;
        int co = rem / 144, k = rem % 144;
        int tap = k / 16, ci = k % 16;
        float w = w2[((size_t)co * C1 + ci) * 9 + tap];
        unsigned short b0 = f2bf(w);
        float r1 = w - bf2f(b0);
        unsigned short b1 = f2bf(r1);
        float r2 = r1 - bf2f(b1);
        unsigned short b2 = f2bf(r2);
        w2b3[j] = (p == 0) ? b0 : (p == 1) ? b1 : b2;
    } else if (gid < 64 * 288 + 4 * 32 * 256 + 1024 + 3 * 32 * 144 + 3 * 16 * 32) {
        int j = gid - (64 * 288 + 4 * 32 * 256 + 1024 + 3 * 32 * 144);
        int p = j / 512, rem = j % 512;
        int co = rem / 32, k = rem % 32;
        float w = (k < 25) ? w1[co * 25 + k] : 0.f;
        unsigned short b0 = f2bf(w);
        float r1 = w - bf2f(b0);
        unsigned short b1 = f2bf(r1);
        float r2 = r1 - bf2f(b1);
        unsigned short b2 = f2bf(r2);
        w1b3[j] = (p == 0) ? b0 : (p == 1) ? b1 : b2;
    }
}

// ---------------- Kernel C: convd via MFMA, co-split for TLP ----------------
// wave: 32co x 32 sites; grid(18, cog=2, 32)
__global__ __launch_bounds__(256) void k_convd(const unsigned short* __restrict__ mem2bf,
                                               const unsigned short* __restrict__ wdb,
                                               const float* __restrict__ bd,
                                               unsigned short* __restrict__ h1bf) {
    int wave = threadIdx.x >> 6;
    int lane = threadIdx.x & 63;
    int col = lane & 31, hi = lane >> 5;
    int cog = blockIdx.y;
    int b = blockIdx.z;
    int n0 = (blockIdx.x * 4 + wave) * 32;
    int site = n0 + col;
    bool sval = site < SITES2;
    int sc = sval ? site : 0;
    int yy = sc / W2, xx = sc % W2;

    const char* ibase = (const char*)(mem2bf + (size_t)b * SITES2 * C2);
    int toff[9];
    bool tval[9];
#pragma unroll
    for (int ky = 0; ky < 3; ++ky)
#pragma unroll
        for (int kx = 0; kx < 3; ++kx) {
            int iy = yy + ky - 1, ix = xx + kx - 1;
            bool v = sval && iy >= 0 && iy < H2 && ix >= 0 && ix < W2;
            tval[ky * 3 + kx] = v;
            toff[ky * 3 + kx] = (iy * W2 + ix) * (C2 * 2);
        }

    const char* abase = (const char*)wdb;
    f32x16 acc = {};
    const s16x8 zero = {0, 0, 0, 0, 0, 0, 0, 0};
#pragma unroll
    for (int s = 0; s < 18; ++s) {
        int tap = s >> 1;
        int boff = (s & 1) * 32 + hi * 16;
        s16x8 bf = tval[tap] ? ld8(ibase + toff[tap] + boff) : zero;
        s16x8 a = ld8(abase + (cog * 32 + col) * 576 + s * 32 + hi * 16);
        acc = __builtin_amdgcn_mfma_f32_32x32x16_bf16(a, bf, acc, 0, 0, 0);
    }
    if (!sval) return;
    char* obase = (char*)(h1bf + ((size_t)b * SITES2 + site) * CD);
#pragma unroll
    for (int q = 0; q < 4; ++q) {
        int co = cog * 32 + 8 * q + 4 * hi;
        float v0 = fmaxf(acc[4 * q + 0] + bd[co + 0], 0.f);
        float v1 = fmaxf(acc[4 * q + 1] + bd[co + 1], 0.f);
        float v2 = fmaxf(acc[4 * q + 2] + bd[co + 2], 0.f);
        float v3 = fmaxf(acc[4 * q + 3] + bd[co + 3], 0.f);
        uint2 u; u.x = pk2(v0, v1); u.y = pk2(v2, v3);
        *(uint2*)(obase + co * 2) = u;
    }
}

// ---------------- Kernel D: convt1 via MFMA ----------------
// block = one 32-site tile; wave = one parity (4 waves = 4 parities share the
// tile's h1 neighborhood through L1). Tile index XCD-swizzled (72 = 8 x 9).
__global__ __launch_bounds__(256) void k_convt1(const unsigned short* __restrict__ h1bf,
                                                const unsigned short* __restrict__ wt1b,
                                                const float* __restrict__ bt1,
                                                unsigned short* __restrict__ h2bf) {
    int par = threadIdx.x >> 6;          // wave = parity
    int lane = threadIdx.x & 63;
    int col = lane & 31, hi = lane >> 5;
    int ry = par >> 1, rx = par & 1;
    int b = blockIdx.z;
    int bx = blockIdx.x;                  // 0..71
    int tile = (bx & 7) * 9 + (bx >> 3);  // bijective XCD swizzle
    int n0 = tile * 32;

    const char* ibase = (const char*)(h1bf + (size_t)b * SITES2 * CD);
    int site = n0 + col;
    bool sv = site < SITES2;
    int sc = sv ? site : 0;
    int m = sc / W2, n = sc % W2;
    int iy1 = m + (ry ? 1 : -1);
    int ix1 = n + (rx ? 1 : -1);
    bool y1v = iy1 >= 0 && iy1 < H2;
    bool x1v = ix1 >= 0 && ix1 < W2;
    int toff[4]; bool tval[4];
#pragma unroll
    for (int t = 0; t < 4; ++t) {
        int ty = t >> 1, tx = t & 1;
        int iy = ty ? iy1 : m;
        int ix = tx ? ix1 : n;
        tval[t] = sv && (ty ? y1v : true) && (tx ? x1v : true);
        toff[t] = (iy * W2 + ix) * (CD * 2);
    }

    const char* abase = (const char*)(wt1b + (size_t)par * 32 * 256);
    f32x16 acc = {};
    const s16x8 zero = {0, 0, 0, 0, 0, 0, 0, 0};
#pragma unroll
    for (int s = 0; s < 16; ++s) {
        int tap = s >> 2;
        int boff = (s & 3) * 32 + hi * 16;
        s16x8 bf = tval[tap] ? ld8(ibase + toff[tap] + boff) : zero;
        s16x8 a = ld8(abase + col * 512 + s * 32 + hi * 16);
        acc = __builtin_amdgcn_mfma_f32_32x32x16_bf16(a, bf, acc, 0, 0, 0);
    }
    if (!sv) return;
    int oy = 2 * m + ry, ox = 2 * n + rx;
    char* obase = (char*)(h2bf + ((size_t)b * SITES1 + (size_t)oy * W1 + ox) * C2);
#pragma unroll
    for (int q = 0; q < 4; ++q) {
        int co = 8 * q + 4 * hi;
        float v0 = fmaxf(acc[4 * q + 0] + bt1[co + 0], 0.f);
        float v1 = fmaxf(acc[4 * q + 1] + bt1[co + 1], 0.f);
        float v2 = fmaxf(acc[4 * q + 2] + bt1[co + 2], 0.f);
        float v3 = fmaxf(acc[4 * q + 3] + bt1[co + 3], 0.f);
        uint2 u; u.x = pk2(v0, v1); u.y = pk2(v2, v3);
        *(uint2*)(obase + co * 2) = u;
    }
}

// ---------------- Kernel E: convt2 VALU, bf16 channel-last input ----------------
__global__ __launch_bounds__(256) void k_convt2(const unsigned short* __restrict__ h2bf,
                                                const float* __restrict__ wt2k,
                                                const float* __restrict__ bt2,
                                                float* __restrict__ out) {
    int i = blockIdx.x * blockDim.x + threadIdx.x;
    if (i >= SITES1) return;
    int par = blockIdx.y;
    int ry = par >> 1, rx = par & 1;
    int b = blockIdx.z;
    int m = i / W1, n = i % W1;
    int iy1 = m + (ry ? 1 : -1);
    int ix1 = n + (rx ? 1 : -1);
    bool y1v = iy1 >= 0 && iy1 < H1;
    bool x1v = ix1 >= 0 && ix1 < W1;

    float a0 = bt2[0], a1 = bt2[1];
    const unsigned short* ib = h2bf + (size_t)b * SITES1 * C2;
#pragma unroll
    for (int t = 0; t < 4; ++t) {
        int ty = t >> 1, tx = t & 1;
        if ((ty && !y1v) || (tx && !x1v)) continue;
        int iy = ty ? iy1 : m;
        int ix = tx ? ix1 : n;
        const unsigned short* p = ib + ((size_t)iy * W1 + ix) * C2;
        const float* w = wt2k + ((size_t)par * 4 + t) * 64;
#pragma unroll
        for (int g = 0; g < 4; ++g) {
            s16x8 v8 = ld8(p + g * 8);
#pragma unroll
            for (int e = 0; e < 8; ++e) {
                float v = bf2f((unsigned short)v8[e]);
                int ci = g * 8 + e;
                a0 += v * w[2 * ci];
                a1 += v * w[2 * ci + 1];
            }
        }
    }
    int oy = 2 * m + ry, ox = 2 * n + rx;
    size_t base_o = (size_t)b * (H0 * W0) + (size_t)oy * W0 + ox;
    out[base_o] = fmaxf(a0, 0.f) + log1pf(expf(-fabsf(a0)));
    out[(size_t)NB * H0 * W0 + base_o] = fmaxf(a1, 0.f) + log1pf(expf(-fabsf(a1)));
}

extern "C" void kernel_launch(void* const* d_in, const int* in_sizes, int n_in,
                              void* d_out, int out_size, void* d_ws, size_t ws_size,
                              hipStream_t stream) {
    const float* x   = (const float*)d_in[0];
    const float* w1  = (const float*)d_in[1];
    const float* w2  = (const float*)d_in[2];
    const float* wd  = (const float*)d_in[3];
    const float* bd  = (const float*)d_in[4];
    const float* wt1 = (const float*)d_in[5];
    const float* bt1 = (const float*)d_in[6];
    const float* wt2 = (const float*)d_in[7];
    const float* bt2 = (const float*)d_in[8];
    float* out = (float*)d_out;

    char* ws = (char*)d_ws;
    // workspace (bytes):
    unsigned char* s1b     = (unsigned char*)(ws);               //  9,420,800 (16t x 2 planes x 294400)
    unsigned short* mem2bf = (unsigned short*)(ws + 9420800);    //  4,710,400
    unsigned short* h1bf   = (unsigned short*)(ws + 14131200);   //  9,420,800
    unsigned short* h2bf   = (unsigned short*)(ws + 23552000);   // 18,841,600
    unsigned long long* xb = (unsigned long long*)(ws + 42393600); // 2,457,600
    unsigned short* wdb    = (unsigned short*)(ws + 44851200);   //     36,864
    unsigned short* wt1b   = (unsigned short*)(ws + 44888064);   //     65,536
    float* wt2k            = (float*)(ws + 44953600);            //      4,096
    unsigned short* w2b3   = (unsigned short*)(ws + 44957696);   //     27,648
    unsigned short* w1b3   = (unsigned short*)(ws + 44985344);   //      3,072
    unsigned int* bm       = (unsigned int*)(ws + 44988416);     // 18,841,600 -> ends 63,830,016

    {
        int n = 64 * 288 + 4 * 32 * 256 + 1024 + 3 * 32 * 144 + 3 * 16 * 32; // 67584
        k_repackb<<<(n + 255) / 256, 256, 0, stream>>>(wd, wt1, wt2, w2, w1,
                                                       wdb, wt1b, wt2k, w2b3, w1b3);
    }
    {
        // 307200 words / 4 waves per block = 76800 blocks exactly
        k_pack<<<76800, 256, 0, stream>>>(x, xb);
    }
    {
        // 16*294400/256 = 18400 blocks exactly
        k_mask<<<18400, 256, 0, stream>>>(xb, bm);
    }
    {
        // 294400 sites / 64 per wave / 4 waves per block = 1150 blocks exactly
        k_snn1<<<1150, 256, 0, stream>>>(bm, w1b3, s1b);
    }
    {
        // 73600 sites / 32 per wave / 4 waves per block = 575 blocks exactly
        k_snn2<<<575, 256, 0, stream>>>(s1b, w2b3, mem2bf);
    }
    {
        dim3 g(18, 2, NB);
        k_convd<<<g, 256, 0, stream>>>(mem2bf, wdb, bd, h1bf);
    }
    {
        // 72 site-tiles (8 XCD chunks x 9), 4 parities as the block's 4 waves
        dim3 g(72, 1, NB);
        k_convt1<<<g, 256, 0, stream>>>(h1bf, wt1b, bt1, h2bf);
    }
    {
        dim3 g(36, 4, NB);
        k_convt2<<<g, 256, 0, stream>>>(h2bf, wt2k, bt2, out);
    }
}

// Round 10
// 208.554 us; speedup vs baseline: 1.0321x; 1.0196x over previous
//
#include <hip/hip_runtime.h>
#include <hip/hip_bf16.h>
#include <cstddef>

// Shapes (fixed):
// x_seq: (T=16, B=32, 1, 100, 368) binary {0,1} fp32
// conv1: w1 (16,1,5,5) s2 p2   -> (32,16,50,184)  [MFMA bf16 3-term split, LIF in acc]
// conv2: w2 (32,16,3,3) s2 p1  -> (32,32,25,92)   [MFMA bf16 3-term split, LIF in acc]
// convd: wd (64,32,3,3) s1 p1  -> (32,64,25,92), relu        [MFMA bf16, co-split, reg-prefetch]
// convT1: wt1 (64,32,4,4) s2 p1 -> (32,32,50,184), relu      [MFMA bf16, parity-per-wave, reg-prefetch]
// convT2: wt2 (32,2,4,4) s2 p1  -> (32,2,100,368), softplus  [VALU, bf16 reads]

#define T_STEPS 16
#define NB 32
#define H0 100
#define W0 368
#define C1 16
#define H1 50
#define W1 184
#define C2 32
#define H2 25
#define W2 92
#define CD 64
#define WPR 6
#define SITES2 2300   // 25*92
#define SITES1 9200   // 50*184
#define NPOS1 (NB * H1 * W1)   // 294400

using f32x16 = __attribute__((ext_vector_type(16))) float;
using f32x4  = __attribute__((ext_vector_type(4))) float;
using s16x8  = __attribute__((ext_vector_type(8))) short;

__device__ inline unsigned short f2bf(float f) {
    union { float f; unsigned int u; } v; v.f = f;
    unsigned int r = v.u + 0x7fffu + ((v.u >> 16) & 1u);  // RNE
    return (unsigned short)(r >> 16);
}
__device__ inline float bf2f(unsigned short u) {
    union { unsigned int u; float f; } v; v.u = ((unsigned int)u) << 16;
    return v.f;
}
__device__ inline unsigned int pk2(float a, float b) {
    return (unsigned int)f2bf(a) | ((unsigned int)f2bf(b) << 16);
}
__device__ inline s16x8 ld8(const void* p) { return *reinterpret_cast<const s16x8*>(p); }

// ---------------- Kernel P: bit-pack binary input ----------------
__global__ __launch_bounds__(256) void k_pack(const float* __restrict__ x,
                                              unsigned long long* __restrict__ xb) {
    int widx = blockIdx.x * 4 + (threadIdx.x >> 6);   // word index (wave-uniform)
    int lane = threadIdx.x & 63;
    int rowid = widx / WPR;                           // uniform const-div
    int wcol  = widx - rowid * WPR;
    int col = (wcol << 6) + lane;
    const float* rp = x + (size_t)rowid * W0;
    float v = 0.f;
    if (col < W0) v = rp[col];
    unsigned long long m = __ballot(v != 0.f);
    if (lane == 0) xb[widx] = m;
}

// ---------------- Kernel M: build 25-bit tap masks for all (t, site) ----------------
__global__ __launch_bounds__(256) void k_mask(const unsigned long long* __restrict__ xb,
                                              unsigned int* __restrict__ bm) {
    int gid = blockIdx.x * blockDim.x + threadIdx.x;
    int t = gid / NPOS1;
    int site = gid - t * NPOS1;
    int x1 = site % W1;
    int tq = site / W1;
    int y1 = tq % H1;
    int b  = tq / H1;
    const int iy0 = 2 * y1 - 2;
    const int ix0 = 2 * x1 - 2;
    const int wi = ix0 >> 6;
    const int sh = ix0 & 63;
    const unsigned long long* xp = xb + ((size_t)(t * NB + b) * H0) * WPR;
    unsigned int bits25 = 0;
#pragma unroll
    for (int ky = 0; ky < 5; ++ky) {
        int iy = iy0 + ky;
        if (iy < 0 || iy >= H0) continue;
        const unsigned long long* row = xp + (size_t)iy * WPR;
        unsigned long long a = (wi >= 0) ? row[wi] : 0ull;
        unsigned long long bw = (wi + 1 < WPR) ? row[wi + 1] : 0ull;
        unsigned long long chunk = a >> sh;
        if (sh) chunk |= (bw << (64 - sh));
        bits25 |= ((unsigned int)chunk & 31u) << (5 * ky);
    }
    bm[gid] = bits25;
}

// ---------------- Kernel A: conv1+LIF fused MFMA over 16 timesteps ----------------
__global__ __launch_bounds__(256) void k_snn1(const unsigned int* __restrict__ bm,
                                              const unsigned short* __restrict__ w1b3,
                                              unsigned char* __restrict__ s1b) {
    __shared__ uint4 lut[256];
    {
        int m = (int)threadIdx.x;  // exactly 256 threads
        unsigned int wv[4];
#pragma unroll
        for (int h = 0; h < 4; ++h) {
            unsigned int lo = (m >> (2 * h)) & 1u, hb = (m >> (2 * h + 1)) & 1u;
            wv[h] = (lo ? 0x3F80u : 0u) | (hb ? 0x3F800000u : 0u);
        }
        lut[m] = make_uint4(wv[0], wv[1], wv[2], wv[3]);
    }
    __syncthreads();

    int wave = threadIdx.x >> 6;
    int lane = threadIdx.x & 63;
    int col = lane & 15;   // site within group / A row (co)
    int hi  = lane >> 4;   // k-slice index
    int base = (blockIdx.x * 4 + wave) * 64;

    s16x8 af0 = ld8((const char*)w1b3 + (size_t)((0 * 16 + col) * 32 + hi * 8) * 2);
    s16x8 af1 = ld8((const char*)w1b3 + (size_t)((1 * 16 + col) * 32 + hi * 8) * 2);
    s16x8 af2 = ld8((const char*)w1b3 + (size_t)((2 * 16 + col) * 32 + hi * 8) * 2);

    f32x4 acc0 = {}, acc1 = {}, acc2 = {}, acc3 = {};

    unsigned int cm0, cm1, cm2, cm3;
    {
        const unsigned int* bp = bm + base;
        cm0 = bp[col]; cm1 = bp[16 + col]; cm2 = bp[32 + col]; cm3 = bp[48 + col];
    }

    for (int t = 0; t < T_STEPS; ++t) {
        unsigned int nm0 = 0, nm1 = 0, nm2 = 0, nm3 = 0;
        if (t < T_STEPS - 1) {
            const unsigned int* bp = bm + (size_t)(t + 1) * NPOS1 + base;
            nm0 = bp[col]; nm1 = bp[16 + col]; nm2 = bp[32 + col]; nm3 = bp[48 + col];
        }
#pragma unroll
        for (int e = 0; e < 4; ++e) {
            acc0[e] *= 0.5f; acc1[e] *= 0.5f; acc2[e] *= 0.5f; acc3[e] *= 0.5f;
        }
#pragma unroll
        for (int g = 0; g < 4; ++g) {
            unsigned int sb = (g == 0) ? cm0 : (g == 1) ? cm1 : (g == 2) ? cm2 : cm3;
            unsigned int byte = (sb >> (hi * 8)) & 0xFFu;
            s16x8 bf = *reinterpret_cast<const s16x8*>(&lut[byte]);
            f32x4& ac = (g == 0) ? acc0 : (g == 1) ? acc1 : (g == 2) ? acc2 : acc3;
            ac = __builtin_amdgcn_mfma_f32_16x16x32_bf16(af0, bf, ac, 0, 0, 0);
            ac = __builtin_amdgcn_mfma_f32_16x16x32_bf16(af1, bf, ac, 0, 0, 0);
            ac = __builtin_amdgcn_mfma_f32_16x16x32_bf16(af2, bf, ac, 0, 0, 0);
        }
#pragma unroll
        for (int g = 0; g < 4; ++g) {
            f32x4& ac = (g == 0) ? acc0 : (g == 1) ? acc1 : (g == 2) ? acc2 : acc3;
            unsigned int nib = 0;
#pragma unroll
            for (int e = 0; e < 4; ++e) {
                float v = ac[e];
                bool s = (v >= 1.0f);
                if (s) nib |= (1u << e);
                ac[e] = s ? 0.f : v;
            }
            unsigned int mk = nib << ((hi & 1) * 4);   // co = hi*4+e
            mk |= __shfl_xor(mk, 16, 64);
            if (hi == 0)
                s1b[(size_t)(t * 2 + 0) * NPOS1 + base + g * 16 + col] = (unsigned char)mk;
            else if (hi == 2)
                s1b[(size_t)(t * 2 + 1) * NPOS1 + base + g * 16 + col] = (unsigned char)mk;
        }
        cm0 = nm0; cm1 = nm1; cm2 = nm2; cm3 = nm3;
    }
}

// ---------------- Kernel B: conv2+LIF fused MFMA over 16 timesteps ----------------
// Next-timestep spike masks prefetched during current MFMA block.
__global__ __launch_bounds__(256) void k_snn2(const unsigned char* __restrict__ s1b,
                                              const unsigned short* __restrict__ w2b3,
                                              unsigned short* __restrict__ mem2bf) {
    __shared__ uint4 lut[256];
    {
        int m = (int)threadIdx.x;
        unsigned int wv[4];
#pragma unroll
        for (int h = 0; h < 4; ++h) {
            unsigned int lo = (m >> (2 * h)) & 1u, hb = (m >> (2 * h + 1)) & 1u;
            wv[h] = (lo ? 0x3F80u : 0u) | (hb ? 0x3F800000u : 0u);
        }
        lut[m] = make_uint4(wv[0], wv[1], wv[2], wv[3]);
    }
    __syncthreads();

    int wave = threadIdx.x >> 6;
    int lane = threadIdx.x & 63;
    int col = lane & 31, hi = lane >> 5;
    int gsite = (blockIdx.x * 4 + wave) * 32 + col;
    int b = gsite / SITES2;
    int rest = gsite % SITES2;
    int y2 = rest / W2, x2 = rest % W2;

    int toff[9]; bool tval[9];
#pragma unroll
    for (int ky = 0; ky < 3; ++ky)
#pragma unroll
        for (int kx = 0; kx < 3; ++kx) {
            int iy = 2 * y2 + ky - 1, ix = 2 * x2 + kx - 1;
            tval[ky * 3 + kx] = iy >= 0 && iy < H1 && ix >= 0 && ix < W1;
            toff[ky * 3 + kx] = iy * W1 + ix;
        }

    const char* ab = (const char*)w2b3;
    s16x8 a0[9], a1[9], a2[9];
#pragma unroll
    for (int s = 0; s < 9; ++s) {
        int ko = (s * 16 + hi * 8) * 2;
        a0[s] = ld8(ab + (col * 144) * 2 + ko);
        a1[s] = ld8(ab + ((32 + col) * 144) * 2 + ko);
        a2[s] = ld8(ab + ((64 + col) * 144) * 2 + ko);
    }

    f32x16 acc = {};

    unsigned int msk[9];
    {
        const unsigned char* spk = s1b + (size_t)hi * NPOS1 + (size_t)b * (H1 * W1);
#pragma unroll
        for (int i = 0; i < 9; ++i)
            msk[i] = tval[i] ? (unsigned int)spk[toff[i]] : 0u;
    }

    for (int t = 0; t < T_STEPS; ++t) {
        unsigned int nmsk[9];
#pragma unroll
        for (int i = 0; i < 9; ++i) nmsk[i] = 0u;
        if (t < T_STEPS - 1) {
            const unsigned char* spk = s1b + (size_t)((t + 1) * 2 + hi) * NPOS1 + (size_t)b * (H1 * W1);
#pragma unroll
            for (int i = 0; i < 9; ++i)
                nmsk[i] = tval[i] ? (unsigned int)spk[toff[i]] : 0u;
        }

#pragma unroll
        for (int e = 0; e < 16; ++e) acc[e] *= 0.5f;

#pragma unroll
        for (int s = 0; s < 9; ++s) {
            s16x8 bf = *reinterpret_cast<const s16x8*>(&lut[msk[s]]);
            acc = __builtin_amdgcn_mfma_f32_32x32x16_bf16(a0[s], bf, acc, 0, 0, 0);
            acc = __builtin_amdgcn_mfma_f32_32x32x16_bf16(a1[s], bf, acc, 0, 0, 0);
            acc = __builtin_amdgcn_mfma_f32_32x32x16_bf16(a2[s], bf, acc, 0, 0, 0);
        }
#pragma unroll
        for (int e = 0; e < 16; ++e) {
            float v = acc[e];
            acc[e] = (v >= 1.0f) ? 0.f : v;
        }
#pragma unroll
        for (int i = 0; i < 9; ++i) msk[i] = nmsk[i];
    }

    char* obase = (char*)(mem2bf + (size_t)gsite * C2);
#pragma unroll
    for (int q = 0; q < 4; ++q) {
        int co = 8 * q + 4 * hi;
        uint2 u;
        u.x = pk2(acc[4 * q + 0], acc[4 * q + 1]);
        u.y = pk2(acc[4 * q + 2], acc[4 * q + 3]);
        *(uint2*)(obase + co * 2) = u;
    }
}

// ---------------- Kernel R: repack weights ----------------
__global__ __launch_bounds__(256) void k_repackb(const float* __restrict__ wd,
                                                 const float* __restrict__ wt1,
                                                 const float* __restrict__ wt2,
                                                 const float* __restrict__ w2,
                                                 const float* __restrict__ w1,
                                                 unsigned short* __restrict__ wdb,
                                                 unsigned short* __restrict__ wt1b,
                                                 float* __restrict__ wt2k,
                                                 unsigned short* __restrict__ w2b3,
                                                 unsigned short* __restrict__ w1b3) {
    int gid = blockIdx.x * blockDim.x + threadIdx.x;
    if (gid < 64 * 288) {
        int co = gid / 288, k = gid % 288;
        int tap = k >> 5, ci = k & 31;
        wdb[gid] = f2bf(wd[((size_t)co * C2 + ci) * 9 + tap]);
    } else if (gid < 64 * 288 + 4 * 32 * 256) {
        int j = gid - 64 * 288;
        int par = j >> 13, co = (j >> 8) & 31, k = j & 255;
        int tap = k >> 6, ci = k & 63;
        int ty = tap >> 1, tx = tap & 1;
        int ry = par >> 1, rx = par & 1;
        int ky = ry ? (ty ? 0 : 2) : (ty ? 3 : 1);
        int kx = rx ? (tx ? 0 : 2) : (tx ? 3 : 1);
        wt1b[j] = f2bf(wt1[(((size_t)ci * 32 + co) * 4 + ky) * 4 + kx]);
    } else if (gid < 64 * 288 + 4 * 32 * 256 + 1024) {
        int j = gid - (64 * 288 + 4 * 32 * 256);
        int par = j >> 8, tap = (j >> 6) & 3, ci = (j >> 1) & 31, co = j & 1;
        int ty = tap >> 1, tx = tap & 1;
        int ry = par >> 1, rx = par & 1;
        int ky = ry ? (ty ? 0 : 2) : (ty ? 3 : 1);
        int kx = rx ? (tx ? 0 : 2) : (tx ? 3 : 1);
        wt2k[j] = wt2[(((size_t)ci * 2 + co) * 4 + ky) * 4 + kx];
    } else if (gid < 64 * 288 + 4 * 32 * 256 + 1024 + 3 * 32 * 144) {
        int j = gid - (64 * 288 + 4 * 32 * 256 + 1024);
        int p = j / 4608, rem = j % 4608;
        int co = rem / 144, k = rem % 144;
        int tap = k / 16, ci = k % 16;
        float w = w2[((size_t)co * C1 + ci) * 9 + tap];
        unsigned short b0 = f2bf(w);
        float r1 = w - bf2f(b0);
        unsigned short b1 = f2bf(r1);
        float r2 = r1 - bf2f(b1);
        unsigned short b2 = f2bf(r2);
        w2b3[j] = (p == 0) ? b0 : (p == 1) ? b1 : b2;
    } else if (gid < 64 * 288 + 4 * 32 * 256 + 1024 + 3 * 32 * 144 + 3 * 16 * 32) {
        int j = gid - (64 * 288 + 4 * 32 * 256 + 1024 + 3 * 32 * 144);
        int p = j / 512, rem = j % 512;
        int co = rem / 32, k = rem % 32;
        float w = (k < 25) ? w1[co * 25 + k] : 0.f;
        unsigned short b0 = f2bf(w);
        float r1 = w - bf2f(b0);
        unsigned short b1 = f2bf(r1);
        float r2 = r1 - bf2f(b1);
        unsigned short b2 = f2bf(r2);
        w1b3[j] = (p == 0) ? b0 : (p == 1) ? b1 : b2;
    }
}

// ---------------- Kernel C: convd via MFMA, co-split, full register prefetch ----------------
// wave: 32co x 32 sites; grid(18, cog=2, 32)
__global__ __launch_bounds__(256) void k_convd(const unsigned short* __restrict__ mem2bf,
                                               const unsigned short* __restrict__ wdb,
                                               const float* __restrict__ bd,
                                               unsigned short* __restrict__ h1bf) {
    int wave = threadIdx.x >> 6;
    int lane = threadIdx.x & 63;
    int col = lane & 31, hi = lane >> 5;
    int cog = blockIdx.y;
    int b = blockIdx.z;
    int n0 = (blockIdx.x * 4 + wave) * 32;
    int site = n0 + col;
    bool sval = site < SITES2;
    int sc = sval ? site : 0;
    int yy = sc / W2, xx = sc % W2;

    const char* ibase = (const char*)(mem2bf + (size_t)b * SITES2 * C2);
    int toff[9];
    bool tval[9];
#pragma unroll
    for (int ky = 0; ky < 3; ++ky)
#pragma unroll
        for (int kx = 0; kx < 3; ++kx) {
            int iy = yy + ky - 1, ix = xx + kx - 1;
            bool v = sval && iy >= 0 && iy < H2 && ix >= 0 && ix < W2;
            tval[ky * 3 + kx] = v;
            toff[ky * 3 + kx] = (iy * W2 + ix) * (C2 * 2);
        }

    const s16x8 zero = {0, 0, 0, 0, 0, 0, 0, 0};
    // prefetch ALL B fragments (18 independent scattered gathers in flight)
    s16x8 bfr[18];
#pragma unroll
    for (int s = 0; s < 18; ++s) {
        int tap = s >> 1;
        int boff = (s & 1) * 32 + hi * 16;
        bfr[s] = tval[tap] ? ld8(ibase + toff[tap] + boff) : zero;
    }
    // prefetch ALL A fragments (L2-resident weights)
    const char* abase = (const char*)wdb + (size_t)(cog * 32 + col) * 576 + hi * 16;
    s16x8 ar[18];
#pragma unroll
    for (int s = 0; s < 18; ++s)
        ar[s] = ld8(abase + s * 32);

    f32x16 acc = {};
#pragma unroll
    for (int s = 0; s < 18; ++s)
        acc = __builtin_amdgcn_mfma_f32_32x32x16_bf16(ar[s], bfr[s], acc, 0, 0, 0);

    if (!sval) return;
    char* obase = (char*)(h1bf + ((size_t)b * SITES2 + site) * CD);
#pragma unroll
    for (int q = 0; q < 4; ++q) {
        int co = cog * 32 + 8 * q + 4 * hi;
        float v0 = fmaxf(acc[4 * q + 0] + bd[co + 0], 0.f);
        float v1 = fmaxf(acc[4 * q + 1] + bd[co + 1], 0.f);
        float v2 = fmaxf(acc[4 * q + 2] + bd[co + 2], 0.f);
        float v3 = fmaxf(acc[4 * q + 3] + bd[co + 3], 0.f);
        uint2 u; u.x = pk2(v0, v1); u.y = pk2(v2, v3);
        *(uint2*)(obase + co * 2) = u;
    }
}

// ---------------- Kernel D: convt1 via MFMA, parity-per-wave, full register prefetch ----------------
// block = one 32-site tile; wave = one parity. Tile index XCD-swizzled (72 = 8 x 9).
__global__ __launch_bounds__(256) void k_convt1(const unsigned short* __restrict__ h1bf,
                                                const unsigned short* __restrict__ wt1b,
                                                const float* __restrict__ bt1,
                                                unsigned short* __restrict__ h2bf) {
    int par = threadIdx.x >> 6;          // wave = parity
    int lane = threadIdx.x & 63;
    int col = lane & 31, hi = lane >> 5;
    int ry = par >> 1, rx = par & 1;
    int b = blockIdx.z;
    int bx = blockIdx.x;                  // 0..71
    int tile = (bx & 7) * 9 + (bx >> 3);  // bijective XCD swizzle
    int n0 = tile * 32;

    const char* ibase = (const char*)(h1bf + (size_t)b * SITES2 * CD);
    int site = n0 + col;
    bool sv = site < SITES2;
    int sc = sv ? site : 0;
    int m = sc / W2, n = sc % W2;
    int iy1 = m + (ry ? 1 : -1);
    int ix1 = n + (rx ? 1 : -1);
    bool y1v = iy1 >= 0 && iy1 < H2;
    bool x1v = ix1 >= 0 && ix1 < W2;
    int toff[4]; bool tval[4];
#pragma unroll
    for (int t = 0; t < 4; ++t) {
        int ty = t >> 1, tx = t & 1;
        int iy = ty ? iy1 : m;
        int ix = tx ? ix1 : n;
        tval[t] = sv && (ty ? y1v : true) && (tx ? x1v : true);
        toff[t] = (iy * W2 + ix) * (CD * 2);
    }

    const s16x8 zero = {0, 0, 0, 0, 0, 0, 0, 0};
    // prefetch ALL B fragments (16 independent scattered gathers in flight)
    s16x8 bfr[16];
#pragma unroll
    for (int s = 0; s < 16; ++s) {
        int tap = s >> 2;
        int boff = (s & 3) * 32 + hi * 16;
        bfr[s] = tval[tap] ? ld8(ibase + toff[tap] + boff) : zero;
    }
    // prefetch ALL A fragments
    const char* abase = (const char*)(wt1b + (size_t)par * 32 * 256) + (size_t)col * 512 + hi * 16;
    s16x8 ar[16];
#pragma unroll
    for (int s = 0; s < 16; ++s)
        ar[s] = ld8(abase + s * 32);

    f32x16 acc = {};
#pragma unroll
    for (int s = 0; s < 16; ++s)
        acc = __builtin_amdgcn_mfma_f32_32x32x16_bf16(ar[s], bfr[s], acc, 0, 0, 0);

    if (!sv) return;
    int oy = 2 * m + ry, ox = 2 * n + rx;
    char* obase = (char*)(h2bf + ((size_t)b * SITES1 + (size_t)oy * W1 + ox) * C2);
#pragma unroll
    for (int q = 0; q < 4; ++q) {
        int co = 8 * q + 4 * hi;
        float v0 = fmaxf(acc[4 * q + 0] + bt1[co + 0], 0.f);
        float v1 = fmaxf(acc[4 * q + 1] + bt1[co + 1], 0.f);
        float v2 = fmaxf(acc[4 * q + 2] + bt1[co + 2], 0.f);
        float v3 = fmaxf(acc[4 * q + 3] + bt1[co + 3], 0.f);
        uint2 u; u.x = pk2(v0, v1); u.y = pk2(v2, v3);
        *(uint2*)(obase + co * 2) = u;
    }
}

// ---------------- Kernel E: convt2 VALU, bf16 channel-last input ----------------
__global__ __launch_bounds__(256) void k_convt2(const unsigned short* __restrict__ h2bf,
                                                const float* __restrict__ wt2k,
                                                const float* __restrict__ bt2,
                                                float* __restrict__ out) {
    int i = blockIdx.x * blockDim.x + threadIdx.x;
    if (i >= SITES1) return;
    int par = blockIdx.y;
    int ry = par >> 1, rx = par & 1;
    int b = blockIdx.z;
    int m = i / W1, n = i % W1;
    int iy1 = m + (ry ? 1 : -1);
    int ix1 = n + (rx ? 1 : -1);
    bool y1v = iy1 >= 0 && iy1 < H1;
    bool x1v = ix1 >= 0 && ix1 < W1;

    float a0 = bt2[0], a1 = bt2[1];
    const unsigned short* ib = h2bf + (size_t)b * SITES1 * C2;
#pragma unroll
    for (int t = 0; t < 4; ++t) {
        int ty = t >> 1, tx = t & 1;
        if ((ty && !y1v) || (tx && !x1v)) continue;
        int iy = ty ? iy1 : m;
        int ix = tx ? ix1 : n;
        const unsigned short* p = ib + ((size_t)iy * W1 + ix) * C2;
        const float* w = wt2k + ((size_t)par * 4 + t) * 64;
#pragma unroll
        for (int g = 0; g < 4; ++g) {
            s16x8 v8 = ld8(p + g * 8);
#pragma unroll
            for (int e = 0; e < 8; ++e) {
                float v = bf2f((unsigned short)v8[e]);
                int ci = g * 8 + e;
                a0 += v * w[2 * ci];
                a1 += v * w[2 * ci + 1];
            }
        }
    }
    int oy = 2 * m + ry, ox = 2 * n + rx;
    size_t base_o = (size_t)b * (H0 * W0) + (size_t)oy * W0 + ox;
    out[base_o] = fmaxf(a0, 0.f) + log1pf(expf(-fabsf(a0)));
    out[(size_t)NB * H0 * W0 + base_o] = fmaxf(a1, 0.f) + log1pf(expf(-fabsf(a1)));
}

extern "C" void kernel_launch(void* const* d_in, const int* in_sizes, int n_in,
                              void* d_out, int out_size, void* d_ws, size_t ws_size,
                              hipStream_t stream) {
    const float* x   = (const float*)d_in[0];
    const float* w1  = (const float*)d_in[1];
    const float* w2  = (const float*)d_in[2];
    const float* wd  = (const float*)d_in[3];
    const float* bd  = (const float*)d_in[4];
    const float* wt1 = (const float*)d_in[5];
    const float* bt1 = (const float*)d_in[6];
    const float* wt2 = (const float*)d_in[7];
    const float* bt2 = (const float*)d_in[8];
    float* out = (float*)d_out;

    char* ws = (char*)d_ws;
    // workspace (bytes):
    unsigned char* s1b     = (unsigned char*)(ws);               //  9,420,800 (16t x 2 planes x 294400)
    unsigned short* mem2bf = (unsigned short*)(ws + 9420800);    //  4,710,400
    unsigned short* h1bf   = (unsigned short*)(ws + 14131200);   //  9,420,800
    unsigned short* h2bf   = (unsigned short*)(ws + 23552000);   // 18,841,600
    unsigned long long* xb = (unsigned long long*)(ws + 42393600); // 2,457,600
    unsigned short* wdb    = (unsigned short*)(ws + 44851200);   //     36,864
    unsigned short* wt1b   = (unsigned short*)(ws + 44888064);   //     65,536
    float* wt2k            = (float*)(ws + 44953600);            //      4,096
    unsigned short* w2b3   = (unsigned short*)(ws + 44957696);   //     27,648
    unsigned short* w1b3   = (unsigned short*)(ws + 44985344);   //      3,072
    unsigned int* bm       = (unsigned int*)(ws + 44988416);     // 18,841,600 -> ends 63,830,016

    {
        int n = 64 * 288 + 4 * 32 * 256 + 1024 + 3 * 32 * 144 + 3 * 16 * 32; // 67584
        k_repackb<<<(n + 255) / 256, 256, 0, stream>>>(wd, wt1, wt2, w2, w1,
                                                       wdb, wt1b, wt2k, w2b3, w1b3);
    }
    {
        // 307200 words / 4 waves per block = 76800 blocks exactly
        k_pack<<<76800, 256, 0, stream>>>(x, xb);
    }
    {
        // 16*294400/256 = 18400 blocks exactly
        k_mask<<<18400, 256, 0, stream>>>(xb, bm);
    }
    {
        // 294400 sites / 64 per wave / 4 waves per block = 1150 blocks exactly
        k_snn1<<<1150, 256, 0, stream>>>(bm, w1b3, s1b);
    }
    {
        // 73600 sites / 32 per wave / 4 waves per block = 575 blocks exactly
        k_snn2<<<575, 256, 0, stream>>>(s1b, w2b3, mem2bf);
    }
    {
        dim3 g(18, 2, NB);
        k_convd<<<g, 256, 0, stream>>>(mem2bf, wdb, bd, h1bf);
    }
    {
        // 72 site-tiles (8 XCD chunks x 9), 4 parities as the block's 4 waves
        dim3 g(72, 1, NB);
        k_convt1<<<g, 256, 0, stream>>>(h1bf, wt1b, bt1, h2bf);
    }
    {
        dim3 g(36, 4, NB);
        k_convt2<<<g, 256, 0, stream>>>(h2bf, wt2k, bt2, out);
    }
}

// Round 11
// 208.391 us; speedup vs baseline: 1.0329x; 1.0008x over previous
//
#include <hip/hip_runtime.h>
#include <hip/hip_bf16.h>
#include <cstddef>

// Shapes (fixed):
// x_seq: (T=16, B=32, 1, 100, 368) binary {0,1} fp32
// conv1: w1 (16,1,5,5) s2 p2   -> (32,16,50,184)  [MFMA bf16 3-term split, LIF in acc]
// conv2: w2 (32,16,3,3) s2 p1  -> (32,32,25,92)   [MFMA bf16 3-term split, LIF in acc]
// convd: wd (64,32,3,3) s1 p1  -> (32,64,25,92), relu        [MFMA bf16, co-split, reg-prefetch]
// convT1: wt1 (64,32,4,4) s2 p1 -> (32,32,50,184), relu      [MFMA bf16, parity-per-wave, reg-prefetch]
// convT2: wt2 (32,2,4,4) s2 p1  -> (32,2,100,368), softplus  [VALU, bf16 reads]

#define T_STEPS 16
#define NB 32
#define H0 100
#define W0 368
#define C1 16
#define H1 50
#define W1 184
#define C2 32
#define H2 25
#define W2 92
#define CD 64
#define WPR 6
#define SITES2 2300   // 25*92
#define SITES1 9200   // 50*184
#define NPOS1 (NB * H1 * W1)   // 294400

using f32x16 = __attribute__((ext_vector_type(16))) float;
using f32x4  = __attribute__((ext_vector_type(4))) float;
using s16x8  = __attribute__((ext_vector_type(8))) short;

__device__ inline unsigned short f2bf(float f) {
    union { float f; unsigned int u; } v; v.f = f;
    unsigned int r = v.u + 0x7fffu + ((v.u >> 16) & 1u);  // RNE
    return (unsigned short)(r >> 16);
}
__device__ inline float bf2f(unsigned short u) {
    union { unsigned int u; float f; } v; v.u = ((unsigned int)u) << 16;
    return v.f;
}
__device__ inline unsigned int pk2(float a, float b) {
    return (unsigned int)f2bf(a) | ((unsigned int)f2bf(b) << 16);
}
__device__ inline s16x8 ld8(const void* p) { return *reinterpret_cast<const s16x8*>(p); }

// ---------------- Kernel P: bit-pack binary input ----------------
__global__ __launch_bounds__(256) void k_pack(const float* __restrict__ x,
                                              unsigned long long* __restrict__ xb) {
    int widx = blockIdx.x * 4 + (threadIdx.x >> 6);   // word index (wave-uniform)
    int lane = threadIdx.x & 63;
    int rowid = widx / WPR;                           // uniform const-div
    int wcol  = widx - rowid * WPR;
    int col = (wcol << 6) + lane;
    const float* rp = x + (size_t)rowid * W0;
    float v = 0.f;
    if (col < W0) v = rp[col];
    unsigned long long m = __ballot(v != 0.f);
    if (lane == 0) xb[widx] = m;
}

// ---------------- Kernel M: build 25-bit tap masks for all (t, site) ----------------
__global__ __launch_bounds__(256) void k_mask(const unsigned long long* __restrict__ xb,
                                              unsigned int* __restrict__ bm) {
    int gid = blockIdx.x * blockDim.x + threadIdx.x;
    int t = gid / NPOS1;
    int site = gid - t * NPOS1;
    int x1 = site % W1;
    int tq = site / W1;
    int y1 = tq % H1;
    int b  = tq / H1;
    const int iy0 = 2 * y1 - 2;
    const int ix0 = 2 * x1 - 2;
    const int wi = ix0 >> 6;
    const int sh = ix0 & 63;
    const unsigned long long* xp = xb + ((size_t)(t * NB + b) * H0) * WPR;
    unsigned int bits25 = 0;
#pragma unroll
    for (int ky = 0; ky < 5; ++ky) {
        int iy = iy0 + ky;
        if (iy < 0 || iy >= H0) continue;
        const unsigned long long* row = xp + (size_t)iy * WPR;
        unsigned long long a = (wi >= 0) ? row[wi] : 0ull;
        unsigned long long bw = (wi + 1 < WPR) ? row[wi + 1] : 0ull;
        unsigned long long chunk = a >> sh;
        if (sh) chunk |= (bw << (64 - sh));
        bits25 |= ((unsigned int)chunk & 31u) << (5 * ky);
    }
    bm[gid] = bits25;
}

// ---------------- Kernel A: conv1+LIF fused MFMA over 16 timesteps ----------------
__global__ __launch_bounds__(256) void k_snn1(const unsigned int* __restrict__ bm,
                                              const unsigned short* __restrict__ w1b3,
                                              unsigned char* __restrict__ s1b) {
    __shared__ uint4 lut[256];
    {
        int m = (int)threadIdx.x;  // exactly 256 threads
        unsigned int wv[4];
#pragma unroll
        for (int h = 0; h < 4; ++h) {
            unsigned int lo = (m >> (2 * h)) & 1u, hb = (m >> (2 * h + 1)) & 1u;
            wv[h] = (lo ? 0x3F80u : 0u) | (hb ? 0x3F800000u : 0u);
        }
        lut[m] = make_uint4(wv[0], wv[1], wv[2], wv[3]);
    }
    __syncthreads();

    int wave = threadIdx.x >> 6;
    int lane = threadIdx.x & 63;
    int col = lane & 15;   // site within group / A row (co)
    int hi  = lane >> 4;   // k-slice index
    int base = (blockIdx.x * 4 + wave) * 64;

    s16x8 af0 = ld8((const char*)w1b3 + (size_t)((0 * 16 + col) * 32 + hi * 8) * 2);
    s16x8 af1 = ld8((const char*)w1b3 + (size_t)((1 * 16 + col) * 32 + hi * 8) * 2);
    s16x8 af2 = ld8((const char*)w1b3 + (size_t)((2 * 16 + col) * 32 + hi * 8) * 2);

    f32x4 acc0 = {}, acc1 = {}, acc2 = {}, acc3 = {};

    unsigned int cm0, cm1, cm2, cm3;
    {
        const unsigned int* bp = bm + base;
        cm0 = bp[col]; cm1 = bp[16 + col]; cm2 = bp[32 + col]; cm3 = bp[48 + col];
    }

    for (int t = 0; t < T_STEPS; ++t) {
        unsigned int nm0 = 0, nm1 = 0, nm2 = 0, nm3 = 0;
        if (t < T_STEPS - 1) {
            const unsigned int* bp = bm + (size_t)(t + 1) * NPOS1 + base;
            nm0 = bp[col]; nm1 = bp[16 + col]; nm2 = bp[32 + col]; nm3 = bp[48 + col];
        }
#pragma unroll
        for (int e = 0; e < 4; ++e) {
            acc0[e] *= 0.5f; acc1[e] *= 0.5f; acc2[e] *= 0.5f; acc3[e] *= 0.5f;
        }
#pragma unroll
        for (int g = 0; g < 4; ++g) {
            unsigned int sb = (g == 0) ? cm0 : (g == 1) ? cm1 : (g == 2) ? cm2 : cm3;
            unsigned int byte = (sb >> (hi * 8)) & 0xFFu;
            s16x8 bf = *reinterpret_cast<const s16x8*>(&lut[byte]);
            f32x4& ac = (g == 0) ? acc0 : (g == 1) ? acc1 : (g == 2) ? acc2 : acc3;
            ac = __builtin_amdgcn_mfma_f32_16x16x32_bf16(af0, bf, ac, 0, 0, 0);
            ac = __builtin_amdgcn_mfma_f32_16x16x32_bf16(af1, bf, ac, 0, 0, 0);
            ac = __builtin_amdgcn_mfma_f32_16x16x32_bf16(af2, bf, ac, 0, 0, 0);
        }
#pragma unroll
        for (int g = 0; g < 4; ++g) {
            f32x4& ac = (g == 0) ? acc0 : (g == 1) ? acc1 : (g == 2) ? acc2 : acc3;
            unsigned int nib = 0;
#pragma unroll
            for (int e = 0; e < 4; ++e) {
                float v = ac[e];
                bool s = (v >= 1.0f);
                if (s) nib |= (1u << e);
                ac[e] = s ? 0.f : v;
            }
            unsigned int mk = nib << ((hi & 1) * 4);   // co = hi*4+e
            mk |= __shfl_xor(mk, 16, 64);
            if (hi == 0)
                s1b[(size_t)(t * 2 + 0) * NPOS1 + base + g * 16 + col] = (unsigned char)mk;
            else if (hi == 2)
                s1b[(size_t)(t * 2 + 1) * NPOS1 + base + g * 16 + col] = (unsigned char)mk;
        }
        cm0 = nm0; cm1 = nm1; cm2 = nm2; cm3 = nm3;
    }
}

// ---------------- Kernel B: conv2+LIF fused MFMA over 16 timesteps ----------------
// launch_bounds(256,1): keep all 27 A-fragments resident across the recurrence.
// Per t: all 9 B-fragments expanded first (independent LUT reads), then the
// 27-MFMA chain in the SAME order as before (bit-identical numerics).
__global__ __launch_bounds__(256, 1) void k_snn2(const unsigned char* __restrict__ s1b,
                                                 const unsigned short* __restrict__ w2b3,
                                                 unsigned short* __restrict__ mem2bf) {
    __shared__ uint4 lut[256];
    {
        int m = (int)threadIdx.x;
        unsigned int wv[4];
#pragma unroll
        for (int h = 0; h < 4; ++h) {
            unsigned int lo = (m >> (2 * h)) & 1u, hb = (m >> (2 * h + 1)) & 1u;
            wv[h] = (lo ? 0x3F80u : 0u) | (hb ? 0x3F800000u : 0u);
        }
        lut[m] = make_uint4(wv[0], wv[1], wv[2], wv[3]);
    }
    __syncthreads();

    int wave = threadIdx.x >> 6;
    int lane = threadIdx.x & 63;
    int col = lane & 31, hi = lane >> 5;
    int gsite = (blockIdx.x * 4 + wave) * 32 + col;
    int b = gsite / SITES2;
    int rest = gsite % SITES2;
    int y2 = rest / W2, x2 = rest % W2;

    int toff[9]; bool tval[9];
#pragma unroll
    for (int ky = 0; ky < 3; ++ky)
#pragma unroll
        for (int kx = 0; kx < 3; ++kx) {
            int iy = 2 * y2 + ky - 1, ix = 2 * x2 + kx - 1;
            tval[ky * 3 + kx] = iy >= 0 && iy < H1 && ix >= 0 && ix < W1;
            toff[ky * 3 + kx] = iy * W1 + ix;
        }

    const char* ab = (const char*)w2b3;
    s16x8 a0[9], a1[9], a2[9];
#pragma unroll
    for (int s = 0; s < 9; ++s) {
        int ko = (s * 16 + hi * 8) * 2;
        a0[s] = ld8(ab + (col * 144) * 2 + ko);
        a1[s] = ld8(ab + ((32 + col) * 144) * 2 + ko);
        a2[s] = ld8(ab + ((64 + col) * 144) * 2 + ko);
    }

    f32x16 acc = {};

    unsigned int msk[9];
    {
        const unsigned char* spk = s1b + (size_t)hi * NPOS1 + (size_t)b * (H1 * W1);
#pragma unroll
        for (int i = 0; i < 9; ++i)
            msk[i] = tval[i] ? (unsigned int)spk[toff[i]] : 0u;
    }

    for (int t = 0; t < T_STEPS; ++t) {
        unsigned int nmsk[9];
#pragma unroll
        for (int i = 0; i < 9; ++i) nmsk[i] = 0u;
        if (t < T_STEPS - 1) {
            const unsigned char* spk = s1b + (size_t)((t + 1) * 2 + hi) * NPOS1 + (size_t)b * (H1 * W1);
#pragma unroll
            for (int i = 0; i < 9; ++i)
                nmsk[i] = tval[i] ? (unsigned int)spk[toff[i]] : 0u;
        }

        // expand ALL 9 B-fragments first: independent LDS reads, in flight together
        s16x8 bfr[9];
#pragma unroll
        for (int s = 0; s < 9; ++s)
            bfr[s] = *reinterpret_cast<const s16x8*>(&lut[msk[s]]);

#pragma unroll
        for (int e = 0; e < 16; ++e) acc[e] *= 0.5f;

#pragma unroll
        for (int s = 0; s < 9; ++s) {
            acc = __builtin_amdgcn_mfma_f32_32x32x16_bf16(a0[s], bfr[s], acc, 0, 0, 0);
            acc = __builtin_amdgcn_mfma_f32_32x32x16_bf16(a1[s], bfr[s], acc, 0, 0, 0);
            acc = __builtin_amdgcn_mfma_f32_32x32x16_bf16(a2[s], bfr[s], acc, 0, 0, 0);
        }
#pragma unroll
        for (int e = 0; e < 16; ++e) {
            float v = acc[e];
            acc[e] = (v >= 1.0f) ? 0.f : v;
        }
#pragma unroll
        for (int i = 0; i < 9; ++i) msk[i] = nmsk[i];
    }

    char* obase = (char*)(mem2bf + (size_t)gsite * C2);
#pragma unroll
    for (int q = 0; q < 4; ++q) {
        int co = 8 * q + 4 * hi;
        uint2 u;
        u.x = pk2(acc[4 * q + 0], acc[4 * q + 1]);
        u.y = pk2(acc[4 * q + 2], acc[4 * q + 3]);
        *(uint2*)(obase + co * 2) = u;
    }
}

// ---------------- Kernel R: repack weights ----------------
__global__ __launch_bounds__(256) void k_repackb(const float* __restrict__ wd,
                                                 const float* __restrict__ wt1,
                                                 const float* __restrict__ wt2,
                                                 const float* __restrict__ w2,
                                                 const float* __restrict__ w1,
                                                 unsigned short* __restrict__ wdb,
                                                 unsigned short* __restrict__ wt1b,
                                                 float* __restrict__ wt2k,
                                                 unsigned short* __restrict__ w2b3,
                                                 unsigned short* __restrict__ w1b3) {
    int gid = blockIdx.x * blockDim.x + threadIdx.x;
    if (gid < 64 * 288) {
        int co = gid / 288, k = gid % 288;
        int tap = k >> 5, ci = k & 31;
        wdb[gid] = f2bf(wd[((size_t)co * C2 + ci) * 9 + tap]);
    } else if (gid < 64 * 288 + 4 * 32 * 256) {
        int j = gid - 64 * 288;
        int par = j >> 13, co = (j >> 8) & 31, k = j & 255;
        int tap = k >> 6, ci = k & 63;
        int ty = tap >> 1, tx = tap & 1;
        int ry = par >> 1, rx = par & 1;
        int ky = ry ? (ty ? 0 : 2) : (ty ? 3 : 1);
        int kx = rx ? (tx ? 0 : 2) : (tx ? 3 : 1);
        wt1b[j] = f2bf(wt1[(((size_t)ci * 32 + co) * 4 + ky) * 4 + kx]);
    } else if (gid < 64 * 288 + 4 * 32 * 256 + 1024) {
        int j = gid - (64 * 288 + 4 * 32 * 256);
        int par = j >> 8, tap = (j >> 6) & 3, ci = (j >> 1) & 31, co = j & 1;
        int ty = tap >> 1, tx = tap & 1;
        int ry = par >> 1, rx = par & 1;
        int ky = ry ? (ty ? 0 : 2) : (ty ? 3 : 1);
        int kx = rx ? (tx ? 0 : 2) : (tx ? 3 : 1);
        wt2k[j] = wt2[(((size_t)ci * 2 + co) * 4 + ky) * 4 + kx];
    } else if (gid < 64 * 288 + 4 * 32 * 256 + 1024 + 3 * 32 * 144) {
        int j = gid - (64 * 288 + 4 * 32 * 256 + 1024);
        int p = j / 4608, rem = j % 4608;
        int co = rem / 144, k = rem % 144;
        int tap = k / 16, ci = k % 16;
        float w = w2[((size_t)co * C1 + ci) * 9 + tap];
        unsigned short b0 = f2bf(w);
        float r1 = w - bf2f(b0);
        unsigned short b1 = f2bf(r1);
        float r2 = r1 - bf2f(b1);
        unsigned short b2 = f2bf(r2);
        w2b3[j] = (p == 0) ? b0 : (p == 1) ? b1 : b2;
    } else if (gid < 64 * 288 + 4 * 32 * 256 + 1024 + 3 * 32 * 144 + 3 * 16 * 32) {
        int j = gid - (64 * 288 + 4 * 32 * 256 + 1024 + 3 * 32 * 144);
        int p = j / 512, rem = j % 512;
        int co = rem / 32, k = rem % 32;
        float w = (k < 25) ? w1[co * 25 + k] : 0.f;
        unsigned short b0 = f2bf(w);
        float r1 = w - bf2f(b0);
        unsigned short b1 = f2bf(r1);
        float r2 = r1 - bf2f(b1);
        unsigned short b2 = f2bf(r2);
        w1b3[j] = (p == 0) ? b0 : (p == 1) ? b1 : b2;
    }
}

// ---------------- Kernel C: convd via MFMA, co-split, full register prefetch ----------------
// wave: 32co x 32 sites; grid(18, cog=2, 32)
__global__ __launch_bounds__(256) void k_convd(const unsigned short* __restrict__ mem2bf,
                                               const unsigned short* __restrict__ wdb,
                                               const float* __restrict__ bd,
                                               unsigned short* __restrict__ h1bf) {
    int wave = threadIdx.x >> 6;
    int lane = threadIdx.x & 63;
    int col = lane & 31, hi = lane >> 5;
    int cog = blockIdx.y;
    int b = blockIdx.z;
    int n0 = (blockIdx.x * 4 + wave) * 32;
    int site = n0 + col;
    bool sval = site < SITES2;
    int sc = sval ? site : 0;
    int yy = sc / W2, xx = sc % W2;

    const char* ibase = (const char*)(mem2bf + (size_t)b * SITES2 * C2);
    int toff[9];
    bool tval[9];
#pragma unroll
    for (int ky = 0; ky < 3; ++ky)
#pragma unroll
        for (int kx = 0; kx < 3; ++kx) {
            int iy = yy + ky - 1, ix = xx + kx - 1;
            bool v = sval && iy >= 0 && iy < H2 && ix >= 0 && ix < W2;
            tval[ky * 3 + kx] = v;
            toff[ky * 3 + kx] = (iy * W2 + ix) * (C2 * 2);
        }

    const s16x8 zero = {0, 0, 0, 0, 0, 0, 0, 0};
    s16x8 bfr[18];
#pragma unroll
    for (int s = 0; s < 18; ++s) {
        int tap = s >> 1;
        int boff = (s & 1) * 32 + hi * 16;
        bfr[s] = tval[tap] ? ld8(ibase + toff[tap] + boff) : zero;
    }
    const char* abase = (const char*)wdb + (size_t)(cog * 32 + col) * 576 + hi * 16;
    s16x8 ar[18];
#pragma unroll
    for (int s = 0; s < 18; ++s)
        ar[s] = ld8(abase + s * 32);

    f32x16 acc = {};
#pragma unroll
    for (int s = 0; s < 18; ++s)
        acc = __builtin_amdgcn_mfma_f32_32x32x16_bf16(ar[s], bfr[s], acc, 0, 0, 0);

    if (!sval) return;
    char* obase = (char*)(h1bf + ((size_t)b * SITES2 + site) * CD);
#pragma unroll
    for (int q = 0; q < 4; ++q) {
        int co = cog * 32 + 8 * q + 4 * hi;
        float v0 = fmaxf(acc[4 * q + 0] + bd[co + 0], 0.f);
        float v1 = fmaxf(acc[4 * q + 1] + bd[co + 1], 0.f);
        float v2 = fmaxf(acc[4 * q + 2] + bd[co + 2], 0.f);
        float v3 = fmaxf(acc[4 * q + 3] + bd[co + 3], 0.f);
        uint2 u; u.x = pk2(v0, v1); u.y = pk2(v2, v3);
        *(uint2*)(obase + co * 2) = u;
    }
}

// ---------------- Kernel D: convt1 via MFMA, parity-per-wave, full register prefetch ----------------
// block = one 32-site tile; wave = one parity. Tile index XCD-swizzled (72 = 8 x 9).
__global__ __launch_bounds__(256) void k_convt1(const unsigned short* __restrict__ h1bf,
                                                const unsigned short* __restrict__ wt1b,
                                                const float* __restrict__ bt1,
                                                unsigned short* __restrict__ h2bf) {
    int par = threadIdx.x >> 6;          // wave = parity
    int lane = threadIdx.x & 63;
    int col = lane & 31, hi = lane >> 5;
    int ry = par >> 1, rx = par & 1;
    int b = blockIdx.z;
    int bx = blockIdx.x;                  // 0..71
    int tile = (bx & 7) * 9 + (bx >> 3);  // bijective XCD swizzle
    int n0 = tile * 32;

    const char* ibase = (const char*)(h1bf + (size_t)b * SITES2 * CD);
    int site = n0 + col;
    bool sv = site < SITES2;
    int sc = sv ? site : 0;
    int m = sc / W2, n = sc % W2;
    int iy1 = m + (ry ? 1 : -1);
    int ix1 = n + (rx ? 1 : -1);
    bool y1v = iy1 >= 0 && iy1 < H2;
    bool x1v = ix1 >= 0 && ix1 < W2;
    int toff[4]; bool tval[4];
#pragma unroll
    for (int t = 0; t < 4; ++t) {
        int ty = t >> 1, tx = t & 1;
        int iy = ty ? iy1 : m;
        int ix = tx ? ix1 : n;
        tval[t] = sv && (ty ? y1v : true) && (tx ? x1v : true);
        toff[t] = (iy * W2 + ix) * (CD * 2);
    }

    const s16x8 zero = {0, 0, 0, 0, 0, 0, 0, 0};
    s16x8 bfr[16];
#pragma unroll
    for (int s = 0; s < 16; ++s) {
        int tap = s >> 2;
        int boff = (s & 3) * 32 + hi * 16;
        bfr[s] = tval[tap] ? ld8(ibase + toff[tap] + boff) : zero;
    }
    const char* abase = (const char*)(wt1b + (size_t)par * 32 * 256) + (size_t)col * 512 + hi * 16;
    s16x8 ar[16];
#pragma unroll
    for (int s = 0; s < 16; ++s)
        ar[s] = ld8(abase + s * 32);

    f32x16 acc = {};
#pragma unroll
    for (int s = 0; s < 16; ++s)
        acc = __builtin_amdgcn_mfma_f32_32x32x16_bf16(ar[s], bfr[s], acc, 0, 0, 0);

    if (!sv) return;
    int oy = 2 * m + ry, ox = 2 * n + rx;
    char* obase = (char*)(h2bf + ((size_t)b * SITES1 + (size_t)oy * W1 + ox) * C2);
#pragma unroll
    for (int q = 0; q < 4; ++q) {
        int co = 8 * q + 4 * hi;
        float v0 = fmaxf(acc[4 * q + 0] + bt1[co + 0], 0.f);
        float v1 = fmaxf(acc[4 * q + 1] + bt1[co + 1], 0.f);
        float v2 = fmaxf(acc[4 * q + 2] + bt1[co + 2], 0.f);
        float v3 = fmaxf(acc[4 * q + 3] + bt1[co + 3], 0.f);
        uint2 u; u.x = pk2(v0, v1); u.y = pk2(v2, v3);
        *(uint2*)(obase + co * 2) = u;
    }
}

// ---------------- Kernel E: convt2 VALU, bf16 channel-last input ----------------
__global__ __launch_bounds__(256) void k_convt2(const unsigned short* __restrict__ h2bf,
                                                const float* __restrict__ wt2k,
                                                const float* __restrict__ bt2,
                                                float* __restrict__ out) {
    int i = blockIdx.x * blockDim.x + threadIdx.x;
    if (i >= SITES1) return;
    int par = blockIdx.y;
    int ry = par >> 1, rx = par & 1;
    int b = blockIdx.z;
    int m = i / W1, n = i % W1;
    int iy1 = m + (ry ? 1 : -1);
    int ix1 = n + (rx ? 1 : -1);
    bool y1v = iy1 >= 0 && iy1 < H1;
    bool x1v = ix1 >= 0 && ix1 < W1;

    float a0 = bt2[0], a1 = bt2[1];
    const unsigned short* ib = h2bf + (size_t)b * SITES1 * C2;
#pragma unroll
    for (int t = 0; t < 4; ++t) {
        int ty = t >> 1, tx = t & 1;
        if ((ty && !y1v) || (tx && !x1v)) continue;
        int iy = ty ? iy1 : m;
        int ix = tx ? ix1 : n;
        const unsigned short* p = ib + ((size_t)iy * W1 + ix) * C2;
        const float* w = wt2k + ((size_t)par * 4 + t) * 64;
#pragma unroll
        for (int g = 0; g < 4; ++g) {
            s16x8 v8 = ld8(p + g * 8);
#pragma unroll
            for (int e = 0; e < 8; ++e) {
                float v = bf2f((unsigned short)v8[e]);
                int ci = g * 8 + e;
                a0 += v * w[2 * ci];
                a1 += v * w[2 * ci + 1];
            }
        }
    }
    int oy = 2 * m + ry, ox = 2 * n + rx;
    size_t base_o = (size_t)b * (H0 * W0) + (size_t)oy * W0 + ox;
    out[base_o] = fmaxf(a0, 0.f) + log1pf(expf(-fabsf(a0)));
    out[(size_t)NB * H0 * W0 + base_o] = fmaxf(a1, 0.f) + log1pf(expf(-fabsf(a1)));
}

extern "C" void kernel_launch(void* const* d_in, const int* in_sizes, int n_in,
                              void* d_out, int out_size, void* d_ws, size_t ws_size,
                              hipStream_t stream) {
    const float* x   = (const float*)d_in[0];
    const float* w1  = (const float*)d_in[1];
    const float* w2  = (const float*)d_in[2];
    const float* wd  = (const float*)d_in[3];
    const float* bd  = (const float*)d_in[4];
    const float* wt1 = (const float*)d_in[5];
    const float* bt1 = (const float*)d_in[6];
    const float* wt2 = (const float*)d_in[7];
    const float* bt2 = (const float*)d_in[8];
    float* out = (float*)d_out;

    char* ws = (char*)d_ws;
    // workspace (bytes):
    unsigned char* s1b     = (unsigned char*)(ws);               //  9,420,800 (16t x 2 planes x 294400)
    unsigned short* mem2bf = (unsigned short*)(ws + 9420800);    //  4,710,400
    unsigned short* h1bf   = (unsigned short*)(ws + 14131200);   //  9,420,800
    unsigned short* h2bf   = (unsigned short*)(ws + 23552000);   // 18,841,600
    unsigned long long* xb = (unsigned long long*)(ws + 42393600); // 2,457,600
    unsigned short* wdb    = (unsigned short*)(ws + 44851200);   //     36,864
    unsigned short* wt1b   = (unsigned short*)(ws + 44888064);   //     65,536
    float* wt2k            = (float*)(ws + 44953600);            //      4,096
    unsigned short* w2b3   = (unsigned short*)(ws + 44957696);   //     27,648
    unsigned short* w1b3   = (unsigned short*)(ws + 44985344);   //      3,072
    unsigned int* bm       = (unsigned int*)(ws + 44988416);     // 18,841,600 -> ends 63,830,016

    {
        int n = 64 * 288 + 4 * 32 * 256 + 1024 + 3 * 32 * 144 + 3 * 16 * 32; // 67584
        k_repackb<<<(n + 255) / 256, 256, 0, stream>>>(wd, wt1, wt2, w2, w1,
                                                       wdb, wt1b, wt2k, w2b3, w1b3);
    }
    {
        // 307200 words / 4 waves per block = 76800 blocks exactly
        k_pack<<<76800, 256, 0, stream>>>(x, xb);
    }
    {
        // 16*294400/256 = 18400 blocks exactly
        k_mask<<<18400, 256, 0, stream>>>(xb, bm);
    }
    {
        // 294400 sites / 64 per wave / 4 waves per block = 1150 blocks exactly
        k_snn1<<<1150, 256, 0, stream>>>(bm, w1b3, s1b);
    }
    {
        // 73600 sites / 32 per wave / 4 waves per block = 575 blocks exactly
        k_snn2<<<575, 256, 0, stream>>>(s1b, w2b3, mem2bf);
    }
    {
        dim3 g(18, 2, NB);
        k_convd<<<g, 256, 0, stream>>>(mem2bf, wdb, bd, h1bf);
    }
    {
        // 72 site-tiles (8 XCD chunks x 9), 4 parities as the block's 4 waves
        dim3 g(72, 1, NB);
        k_convt1<<<g, 256, 0, stream>>>(h1bf, wt1b, bt1, h2bf);
    }
    {
        dim3 g(36, 4, NB);
        k_convt2<<<g, 256, 0, stream>>>(h2bf, wt2k, bt2, out);
    }
}